// Round 1
// baseline (362.904 us; speedup 1.0000x reference)
//
#include <hip/hip_runtime.h>

#define BB 64
#define PP 256
#define NN 1000
#define NP 1024   // padded KV rows (power of 2, zero-filled beyond NN)
#define EE 128
#define HH 8
#define DD 16
// H*D = 128

typedef __fp16 v4h __attribute__((ext_vector_type(4)));
typedef float v4f __attribute__((ext_vector_type(4)));

// Shared MFMA GEMM convention (validated in k3/k5 since R2):
//   af = X[m = lane&15][k = 4*(lane>>4)+j]      (v4h)
//   bf = W^T[n = lane&15][k = 4*(lane>>4)+j]    (v4h, from LDS)
//   D  = mfma(af, bf, acc):  acc[r] = C[m = 4*(lane>>4)+r][n = lane&15]

// ---------------------------------------------------------------------------
// k1: Q projection, MFMA.  Qh = 0.25 * (concat(ln, attr) @ Wq), fp16 out.
// attr (K-row 128) applied as rank-1 epilogue update.
// ---------------------------------------------------------------------------
__global__ __launch_bounds__(256) void k1_qproj(const float* __restrict__ ln,
                                                const float* __restrict__ attr,
                                                const float* __restrict__ Wq,
                                                __fp16* __restrict__ Qh) {
    __shared__ __fp16 wt[128 * 132];   // Wq^T[n][k], first 128 k-rows
    __shared__ float attrs[64];
    const int tid = threadIdx.x;
    const int row0 = blockIdx.x * 64;   // 256 blocks
    for (int i = tid; i < 128 * 128; i += 256) {
        int k = i >> 7, n = i & 127;
        wt[n * 132 + k] = (__fp16)Wq[i];
    }
    if (tid < 64) attrs[tid] = attr[row0 + tid];
    __syncthreads();

    const int wid = tid >> 6, lane = tid & 63;
    const int lp = lane & 15, lg = lane >> 4;
    const int rb = row0 + wid * 16;

    const float* arow = ln + (size_t)(rb + lp) * 128;
    v4f acc[8];
#pragma unroll
    for (int cf = 0; cf < 8; cf++) acc[cf] = (v4f){0.f, 0.f, 0.f, 0.f};

#pragma unroll
    for (int k0 = 0; k0 < 8; k0++) {
        float4 av = *(const float4*)&arow[k0 * 16 + 4 * lg];
        v4h af;
        af[0] = (__fp16)av.x; af[1] = (__fp16)av.y;
        af[2] = (__fp16)av.z; af[3] = (__fp16)av.w;
#pragma unroll
        for (int cf = 0; cf < 8; cf++) {
            v4h bf = *(const v4h*)&wt[(cf * 16 + lp) * 132 + k0 * 16 + 4 * lg];
            acc[cf] = __builtin_amdgcn_mfma_f32_16x16x16f16(af, bf, acc[cf], 0, 0, 0);
        }
    }

#pragma unroll
    for (int cf = 0; cf < 8; cf++) {
        const int col = cf * 16 + lp;
        const float w128 = Wq[128 * 128 + col];
#pragma unroll
        for (int r = 0; r < 4; r++) {
            const int rl = wid * 16 + 4 * lg + r;
            float v = (acc[cf][r] + attrs[rl] * w128) * 0.25f;
            Qh[(size_t)(row0 + rl) * 128 + col] = (__fp16)v;
        }
    }
}

// ---------------------------------------------------------------------------
// k2: K/V projection, MFMA.  blockIdx.z: 0 -> Kf [B,H,NP,16], 1 -> Vf [B,H,16,NP].
// Rows padded to NP=1024, zero-filled beyond NN.
// ---------------------------------------------------------------------------
__global__ __launch_bounds__(256) void k2_kv(const float* __restrict__ nodes,
                                             const float* __restrict__ Wk,
                                             const float* __restrict__ Wv,
                                             __fp16* __restrict__ Kf,
                                             __fp16* __restrict__ Vf) {
    __shared__ __fp16 wt[128 * 132];   // W^T[n][k]
    const int tid = threadIdx.x;
    const int b = blockIdx.y;
    const int kv = blockIdx.z;
    const float* W = (kv == 0) ? Wk : Wv;
    for (int i = tid; i < 128 * 128; i += 256) {
        int k = i >> 7, n = i & 127;
        wt[n * 132 + k] = (__fp16)W[i];
    }
    __syncthreads();

    const int wid = tid >> 6, lane = tid & 63;
    const int lp = lane & 15, lg = lane >> 4;
    const int nb = blockIdx.x * 64 + wid * 16;   // 16 x-blocks -> rows 0..1023

    int nr = nb + lp;
    if (nr >= NN) nr = NN - 1;                   // clamp; garbage zeroed on store
    const float* arow = nodes + (size_t)(b * NN + nr) * 128;

    v4f acc[8];
#pragma unroll
    for (int cf = 0; cf < 8; cf++) acc[cf] = (v4f){0.f, 0.f, 0.f, 0.f};

#pragma unroll
    for (int k0 = 0; k0 < 8; k0++) {
        float4 av = *(const float4*)&arow[k0 * 16 + 4 * lg];
        v4h af;
        af[0] = (__fp16)av.x; af[1] = (__fp16)av.y;
        af[2] = (__fp16)av.z; af[3] = (__fp16)av.w;
#pragma unroll
        for (int cf = 0; cf < 8; cf++) {
            v4h bf = *(const v4h*)&wt[(cf * 16 + lp) * 132 + k0 * 16 + 4 * lg];
            acc[cf] = __builtin_amdgcn_mfma_f32_16x16x16f16(af, bf, acc[cf], 0, 0, 0);
        }
    }

    if (kv == 0) {
        // col = h*16 + d: cf = h, lp = d.  Kf[b,h,n,d], n = nb + 4*lg + r
#pragma unroll
        for (int cf = 0; cf < 8; cf++) {
            const size_t base = ((size_t)(b * HH + cf) << 14) + lp;
#pragma unroll
            for (int r = 0; r < 4; r++) {
                const int n = nb + 4 * lg + r;
                Kf[base + (size_t)n * 16] = (n < NN) ? (__fp16)acc[cf][r] : (__fp16)0.f;
            }
        }
    } else {
        // Vf[b,h,d,n]: cf = h, lp = d, n = nb + 4*lg + r (4 consecutive -> v4h)
#pragma unroll
        for (int cf = 0; cf < 8; cf++) {
            v4h pk;
#pragma unroll
            for (int r = 0; r < 4; r++) {
                const int n = nb + 4 * lg + r;
                pk[r] = (n < NN) ? (__fp16)acc[cf][r] : (__fp16)0.f;
            }
            *(v4h*)&Vf[(((size_t)(b * HH + cf) * 16 + lp) << 10) + nb + 4 * lg] = pk;
        }
    }
}

// ---------------------------------------------------------------------------
// k3: MFMA attention, zero LDS, 4 independent head-chains/wave.
// R7: split-KV.  N split into 4 chunks of 256 rows -> grid 2048 = 8 blocks/CU
// (32 waves/CU, whole grid co-resident).  Each block emits per-chunk
// NORMALIZED partial A_c (fp16, bounded by |V|) + chunk denominator l_c (f32).
// Combine (A = sum_c A_c * l_c / sum l_c) is folded into k4.
// ---------------------------------------------------------------------------
__global__ __launch_bounds__(256, 8) void k3_attn(const __fp16* __restrict__ Qh,
                                                  const __fp16* __restrict__ Kf,
                                                  const __fp16* __restrict__ Vf,
                                                  const float* __restrict__ mask,
                                                  __fp16* __restrict__ Ah,
                                                  float* __restrict__ Ls) {
    const int tid = threadIdx.x;
    const int bid = blockIdx.x;            // 2048
    const int b = bid & 63;                // consecutive bids -> XCD round-robin on b
    const int rest = bid >> 6;             // 0..31
    const int c = rest & 7;
    const int chunk = rest >> 3;           // 0..3  (KV rows [chunk*256, chunk*256+256))
    const int hg = c & 1, pt = c >> 1;
    const int h0 = hg * 4;
    const int p0 = pt * 64;

    const int wid = tid >> 6, lane = tid & 63;
    const int lp = lane & 15, lg = lane >> 4;
    const int pw = p0 + wid * 16;

    v4h qf[4];
    {
        const __fp16* qrow = Qh + (size_t)(b * PP + pw + lp) * 128 + h0 * 16 + 4 * lg;
#pragma unroll
        for (int j = 0; j < 4; j++) qf[j] = *(const v4h*)&qrow[j * 16];
    }

    v4f acc[4];
    float lsum[4];
#pragma unroll
    for (int j = 0; j < 4; j++) { acc[j] = (v4f){0.f, 0.f, 0.f, 0.f}; lsum[j] = 0.f; }
    const v4f zero4 = {0.f, 0.f, 0.f, 0.f};

    const __fp16* kp = Kf + ((size_t)(b * HH + h0) << 14);          // [h][n][16]
    const __fp16* vp = Vf + ((size_t)((b * HH + h0) * 16) << 10);   // [h][d][NP]
    const float* mrow = mask + (size_t)(b * PP + pw + lp) * NN;

    const int s0 = chunk << 4;                 // 16 steps per chunk
    const int send = (chunk == 3) ? 62 : s0 + 16;   // chunk 3: 14 full + tail

#pragma unroll 2
    for (int s = s0; s < send; s++) {
        const int nl = s * 16;
        v4h kf[4], vf[4];
#pragma unroll
        for (int j = 0; j < 4; j++)
            kf[j] = *(const v4h*)&kp[(j << 14) + (nl + lp) * 16 + 4 * lg];
#pragma unroll
        for (int j = 0; j < 4; j++)
            vf[j] = *(const v4h*)&vp[(j << 14) + lp * NP + nl + 4 * lg];
        float4 mv = *(const float4*)&mrow[nl + 4 * lg];
#pragma unroll
        for (int j = 0; j < 4; j++) {
            v4f sc = __builtin_amdgcn_mfma_f32_16x16x16f16(kf[j], qf[j], zero4, 0, 0, 0);
            float w0 = __expf(sc[0] + mv.x);
            float w1 = __expf(sc[1] + mv.y);
            float w2 = __expf(sc[2] + mv.z);
            float w3 = __expf(sc[3] + mv.w);
            lsum[j] += (w0 + w1) + (w2 + w3);
            v4h wf;
            wf[0] = (__fp16)w0; wf[1] = (__fp16)w1; wf[2] = (__fp16)w2; wf[3] = (__fp16)w3;
            acc[j] = __builtin_amdgcn_mfma_f32_16x16x16f16(wf, vf[j], acc[j], 0, 0, 0);
        }
    }
    if (chunk == 3) {   // tail step: n = 992 + 4*lg + r
        const int nl = 992;
        int nc = nl + 4 * lg; if (nc > 996) nc = 996;
        float4 mv = *(const float4*)&mrow[nc];
        const bool b0 = (nl + 4 * lg + 0 < NN), b1 = (nl + 4 * lg + 1 < NN);
        const bool b2 = (nl + 4 * lg + 2 < NN), b3 = (nl + 4 * lg + 3 < NN);
#pragma unroll
        for (int j = 0; j < 4; j++) {
            v4h kf = *(const v4h*)&kp[(j << 14) + (nl + lp) * 16 + 4 * lg];
            v4h vf = *(const v4h*)&vp[(j << 14) + lp * NP + nl + 4 * lg];
            v4f sc = __builtin_amdgcn_mfma_f32_16x16x16f16(kf, qf[j], zero4, 0, 0, 0);
            float w0 = b0 ? __expf(sc[0] + mv.x) : 0.f;
            float w1 = b1 ? __expf(sc[1] + mv.y) : 0.f;
            float w2 = b2 ? __expf(sc[2] + mv.z) : 0.f;
            float w3 = b3 ? __expf(sc[3] + mv.w) : 0.f;
            lsum[j] += (w0 + w1) + (w2 + w3);
            v4h wf;
            wf[0] = (__fp16)w0; wf[1] = (__fp16)w1; wf[2] = (__fp16)w2; wf[3] = (__fp16)w3;
            acc[j] = __builtin_amdgcn_mfma_f32_16x16x16f16(wf, vf, acc[j], 0, 0, 0);
        }
    }

    const size_t gbase = (size_t)chunk * (BB * PP) + (size_t)b * PP + pw;
#pragma unroll
    for (int j = 0; j < 4; j++) {
        float l = lsum[j];
        l += __shfl_xor(l, 16);
        l += __shfl_xor(l, 32);
        // lanes 0..15 (lg==0) hold the chunk row-sum for p-rows pw+lp
        if (lg == 0) Ls[(gbase + lp) * HH + h0 + j] = l;
#pragma unroll
        for (int r = 0; r < 4; r++) {
            float denom = __shfl(l, 4 * lg + r);
            float inv = (denom > 0.f) ? 1.f / denom : 0.f;   // fully-masked chunk -> 0
            Ah[(gbase + 4 * lg + r) * 128 + (h0 + j) * 16 + lp] =
                (__fp16)(acc[j][r] * inv);
        }
    }
}

// ---------------------------------------------------------------------------
// k4: combine split-KV partials + mh MFMA.
// A[row][h*16+d] = sum_c Ah_c[row][h*16+d] * (Ls_c[row][h] / sum_c Ls_c[row][h])
// Mh = fp16( (A @ Wo + bo) * (1/sqrt(128)) )
// ---------------------------------------------------------------------------
__global__ __launch_bounds__(256) void k4_mh(const __fp16* __restrict__ Ah,
                                             const float* __restrict__ Ls,
                                             const float* __restrict__ Wo,
                                             const float* __restrict__ bo,
                                             __fp16* __restrict__ Mh) {
    __shared__ __fp16 wt[128 * 132];   // Wo^T[n][k]
    const int tid = threadIdx.x;
    const int row0 = blockIdx.x * 64;
    for (int i = tid; i < 128 * 128; i += 256) {
        int k = i >> 7, n = i & 127;
        wt[n * 132 + k] = (__fp16)Wo[i];
    }
    __syncthreads();

    const int wid = tid >> 6, lane = tid & 63;
    const int lp = lane & 15, lg = lane >> 4;
    const int rb = row0 + wid * 16;
    const int g = rb + lp;                 // global row 0..16383

    // per-row per-head combine weights
    float wgt[4][8];
    {
        float l[4][8];
#pragma unroll
        for (int cc = 0; cc < 4; cc++) {
            const float* lr = Ls + ((size_t)cc * (BB * PP) + g) * HH;
            float4 x = *(const float4*)lr;
            float4 y = *(const float4*)(lr + 4);
            l[cc][0] = x.x; l[cc][1] = x.y; l[cc][2] = x.z; l[cc][3] = x.w;
            l[cc][4] = y.x; l[cc][5] = y.y; l[cc][6] = y.z; l[cc][7] = y.w;
        }
#pragma unroll
        for (int h = 0; h < 8; h++) {
            float s = (l[0][h] + l[1][h]) + (l[2][h] + l[3][h]);
            float inv = (s > 0.f) ? 1.f / s : 0.f;
#pragma unroll
            for (int cc = 0; cc < 4; cc++) wgt[cc][h] = l[cc][h] * inv;
        }
    }

    const __fp16* arow = Ah + (size_t)g * 128;
    const size_t CSTR = (size_t)(BB * PP) * 128;   // chunk stride in halfs

    v4f acc[8];
#pragma unroll
    for (int cf = 0; cf < 8; cf++) acc[cf] = (v4f){0.f, 0.f, 0.f, 0.f};

#pragma unroll
    for (int k0 = 0; k0 < 8; k0++) {
        const int off = k0 * 16 + 4 * lg;
        v4h p0v = *(const v4h*)&arow[off];
        v4h p1v = *(const v4h*)&arow[CSTR + off];
        v4h p2v = *(const v4h*)&arow[2 * CSTR + off];
        v4h p3v = *(const v4h*)&arow[3 * CSTR + off];
        v4h af;
#pragma unroll
        for (int e = 0; e < 4; e++) {
            float v = (float)p0v[e] * wgt[0][k0] + (float)p1v[e] * wgt[1][k0]
                    + (float)p2v[e] * wgt[2][k0] + (float)p3v[e] * wgt[3][k0];
            af[e] = (__fp16)v;
        }
#pragma unroll
        for (int cf = 0; cf < 8; cf++) {
            v4h bf = *(const v4h*)&wt[(cf * 16 + lp) * 132 + k0 * 16 + 4 * lg];
            acc[cf] = __builtin_amdgcn_mfma_f32_16x16x16f16(af, bf, acc[cf], 0, 0, 0);
        }
    }

    const float scale = 0.08838834764831845f;   // 1/sqrt(128)
#pragma unroll
    for (int cf = 0; cf < 8; cf++) {
        const int col = cf * 16 + lp;
        const float bb = bo[col];
#pragma unroll
        for (int r = 0; r < 4; r++) {
            const int rl = wid * 16 + 4 * lg + r;
            Mh[(size_t)(row0 + rl) * 128 + col] = (__fp16)((acc[cf][r] + bb) * scale);
        }
    }
}

// ---------------------------------------------------------------------------
// k5: final scoring + tanh-clip softmax (R4 structure; mh fp16 pre-scaled)
// ---------------------------------------------------------------------------
__global__ __launch_bounds__(256) void k5_final(const float* __restrict__ nodes,
                                                const __fp16* __restrict__ Mh,
                                                const float* __restrict__ mask,
                                                float* __restrict__ out) {
    __shared__ __fp16 probs[16 * 1028];
    __shared__ float rowsum[16];
    __shared__ float rowinv[16];
    const int tid = threadIdx.x;
    const int bid = blockIdx.x;          // 1024 = 64 b x 16 pt, XCD-swizzled
    const int xcd = bid & 7;
    const int rest = bid >> 3;
    const int pt = rest & 15;
    const int b = ((rest >> 4) << 3) + xcd;
    const int p0 = pt * 16;

    if (tid < 16) rowsum[tid] = 0.f;

    const int wid = tid >> 6, lane = tid & 63;
    const int lp = lane & 15, lg = lane >> 4;

    v4h bf[8];
    {
        const __fp16* mhrow = Mh + (size_t)(b * PP + p0 + lp) * 128;
#pragma unroll
        for (int ec = 0; ec < 8; ec++)
            bf[ec] = *(const v4h*)&mhrow[ec * 16 + 4 * lg];
    }
    __syncthreads();

    float lsum = 0.f;
    const float* nbase = nodes + (size_t)b * NN * 128;
    const float* mkrow = mask + (size_t)(b * PP + p0 + lp) * NN;
    const v4f zero4 = {0.f, 0.f, 0.f, 0.f};

    for (int s = 0; s < 16; s++) {
        const int nt = s * 64 + wid * 16;
        int nr = nt + lp;
        if (nr >= NN) nr = NN - 1;
        const float* arow = nbase + (size_t)nr * 128;
        v4f acc = zero4;
#pragma unroll
        for (int ec = 0; ec < 8; ec++) {
            float4 av = *(const float4*)&arow[ec * 16 + 4 * lg];
            v4h af;
            af[0] = (__fp16)av.x; af[1] = (__fp16)av.y;
            af[2] = (__fp16)av.z; af[3] = (__fp16)av.w;
            acc = __builtin_amdgcn_mfma_f32_16x16x16f16(af, bf[ec], acc, 0, 0, 0);
        }
        const int nb4 = nt + 4 * lg;
        v4h wf;
        if (nt + 15 < NN) {
            float4 mkv = *(const float4*)&mkrow[nb4];
            float e0 = __expf(2.f * acc[0]);
            float e1 = __expf(2.f * acc[1]);
            float e2 = __expf(2.f * acc[2]);
            float e3 = __expf(2.f * acc[3]);
            float w0 = __expf(fmaf(-20.f, __builtin_amdgcn_rcpf(e0 + 1.f), mkv.x));
            float w1 = __expf(fmaf(-20.f, __builtin_amdgcn_rcpf(e1 + 1.f), mkv.y));
            float w2 = __expf(fmaf(-20.f, __builtin_amdgcn_rcpf(e2 + 1.f), mkv.z));
            float w3 = __expf(fmaf(-20.f, __builtin_amdgcn_rcpf(e3 + 1.f), mkv.w));
            lsum += (w0 + w1) + (w2 + w3);
            wf[0] = (__fp16)w0; wf[1] = (__fp16)w1; wf[2] = (__fp16)w2; wf[3] = (__fp16)w3;
        } else {
            float w[4];
#pragma unroll
            for (int r = 0; r < 4; r++) {
                if (nb4 + r < NN) {
                    float e = __expf(2.f * acc[r]);
                    w[r] = __expf(fmaf(-20.f, __builtin_amdgcn_rcpf(e + 1.f),
                                       mkrow[nb4 + r]));
                } else {
                    w[r] = 0.f;
                }
            }
            lsum += (w[0] + w[1]) + (w[2] + w[3]);
            wf[0] = (__fp16)w[0]; wf[1] = (__fp16)w[1];
            wf[2] = (__fp16)w[2]; wf[3] = (__fp16)w[3];
        }
        *(v4h*)&probs[lp * 1028 + nb4] = wf;
    }

    lsum += __shfl_xor(lsum, 16);
    lsum += __shfl_xor(lsum, 32);
    if (lane < 16) atomicAdd(&rowsum[lane], lsum);
    __syncthreads();
    if (tid < 16) rowinv[tid] = 1.f / rowsum[tid];
    __syncthreads();

    if (tid < 250) {
        const int c4 = tid * 4;
        const size_t obase = (size_t)(b * PP + p0) * NN;
#pragma unroll 4
        for (int r = 0; r < 16; r++) {
            v4h pv = *(const v4h*)&probs[r * 1028 + c4];
            float inv = rowinv[r];
            float4 ov;
            ov.x = (float)pv[0] * inv;
            ov.y = (float)pv[1] * inv;
            ov.z = (float)pv[2] * inv;
            ov.w = (float)pv[3] * inv;
            *(float4*)&out[obase + (size_t)r * NN + c4] = ov;
        }
    }
}

extern "C" void kernel_launch(void* const* d_in, const int* in_sizes, int n_in,
                              void* d_out, int out_size, void* d_ws, size_t ws_size,
                              hipStream_t stream) {
    const float* nodes = (const float*)d_in[0];
    const float* ln    = (const float*)d_in[1];
    const float* attr  = (const float*)d_in[2];
    const float* mask  = (const float*)d_in[3];
    const float* Wq    = (const float*)d_in[4];
    const float* Wk    = (const float*)d_in[5];
    const float* Wv    = (const float*)d_in[6];
    const float* Wo    = (const float*)d_in[7];
    const float* bo    = (const float*)d_in[8];
    float* out = (float*)d_out;

    // workspace layout: fp16 Qh, Mh (fp32 Aout no longer needed)
    __fp16* Qh  = (__fp16*)d_ws;                       // 2,097,152 halfs (4.2 MB)
    __fp16* Mhh = Qh + 2097152;                        // 2,097,152 halfs (4.2 MB)

    // d_out doubles as scratch (fully rewritten by k5 every launch):
    //   Kf 16.8MB | Vf 16.8MB | Ah (split-KV partial A, fp16) 16.8MB | Ls 2.1MB
    __fp16* Kf = (__fp16*)d_out;
    __fp16* Vf = Kf + (size_t)BB * HH * NP * 16;
    __fp16* Ah = Vf + (size_t)BB * HH * 16 * NP;
    float*  Ls = (float*)(Ah + (size_t)4 * BB * PP * 128);

    hipLaunchKernelGGL(k1_qproj, dim3(256), dim3(256), 0, stream, ln, attr, Wq, Qh);
    hipLaunchKernelGGL(k2_kv, dim3(16, 64, 2), dim3(256), 0, stream, nodes, Wk, Wv, Kf, Vf);
    hipLaunchKernelGGL(k3_attn, dim3(2048), dim3(256), 0, stream, Qh, Kf, Vf, mask, Ah, Ls);
    hipLaunchKernelGGL(k4_mh, dim3(256), dim3(256), 0, stream, Ah, Ls, Wo, bo, Mhh);
    hipLaunchKernelGGL(k5_final, dim3(1024), dim3(256), 0, stream, nodes, Mhh, mask, out);
}

// Round 4
// 338.692 us; speedup vs baseline: 1.0715x; 1.0715x over previous
//
#include <hip/hip_runtime.h>

#define BB 64
#define PP 256
#define NN 1000
#define NP 1024   // padded KV rows (power of 2, zero-filled beyond NN)
#define EE 128
#define HH 8
#define DD 16
// H*D = 128

typedef __fp16 v4h __attribute__((ext_vector_type(4)));
typedef float v4f __attribute__((ext_vector_type(4)));

// Shared MFMA GEMM convention (validated in k3/k5 since R2):
//   af = X[m = lane&15][k = 4*(lane>>4)+j]      (v4h)
//   bf = W^T[n = lane&15][k = 4*(lane>>4)+j]    (v4h, from LDS)
//   D  = mfma(af, bf, acc):  acc[r] = C[m = 4*(lane>>4)+r][n = lane&15]

// ---------------------------------------------------------------------------
// k1: Q projection, MFMA.  Qh = 0.25 * (concat(ln, attr) @ Wq), fp16 out.
// attr (K-row 128) applied as rank-1 epilogue update.
// ---------------------------------------------------------------------------
__global__ __launch_bounds__(256) void k1_qproj(const float* __restrict__ ln,
                                                const float* __restrict__ attr,
                                                const float* __restrict__ Wq,
                                                __fp16* __restrict__ Qh) {
    __shared__ __fp16 wt[128 * 132];   // Wq^T[n][k], first 128 k-rows
    __shared__ float attrs[64];
    const int tid = threadIdx.x;
    const int row0 = blockIdx.x * 64;   // 256 blocks
    for (int i = tid; i < 128 * 128; i += 256) {
        int k = i >> 7, n = i & 127;
        wt[n * 132 + k] = (__fp16)Wq[i];
    }
    if (tid < 64) attrs[tid] = attr[row0 + tid];
    __syncthreads();

    const int wid = tid >> 6, lane = tid & 63;
    const int lp = lane & 15, lg = lane >> 4;
    const int rb = row0 + wid * 16;

    const float* arow = ln + (size_t)(rb + lp) * 128;
    v4f acc[8];
#pragma unroll
    for (int cf = 0; cf < 8; cf++) acc[cf] = (v4f){0.f, 0.f, 0.f, 0.f};

#pragma unroll
    for (int k0 = 0; k0 < 8; k0++) {
        float4 av = *(const float4*)&arow[k0 * 16 + 4 * lg];
        v4h af;
        af[0] = (__fp16)av.x; af[1] = (__fp16)av.y;
        af[2] = (__fp16)av.z; af[3] = (__fp16)av.w;
#pragma unroll
        for (int cf = 0; cf < 8; cf++) {
            v4h bf = *(const v4h*)&wt[(cf * 16 + lp) * 132 + k0 * 16 + 4 * lg];
            acc[cf] = __builtin_amdgcn_mfma_f32_16x16x16f16(af, bf, acc[cf], 0, 0, 0);
        }
    }

#pragma unroll
    for (int cf = 0; cf < 8; cf++) {
        const int col = cf * 16 + lp;
        const float w128 = Wq[128 * 128 + col];
#pragma unroll
        for (int r = 0; r < 4; r++) {
            const int rl = wid * 16 + 4 * lg + r;
            float v = (acc[cf][r] + attrs[rl] * w128) * 0.25f;
            Qh[(size_t)(row0 + rl) * 128 + col] = (__fp16)v;
        }
    }
}

// ---------------------------------------------------------------------------
// k2: K/V projection, MFMA.  blockIdx.z: 0 -> Kf [B,H,NP,16], 1 -> Vf [B,H,16,NP].
// Rows padded to NP=1024, zero-filled beyond NN.
// ---------------------------------------------------------------------------
__global__ __launch_bounds__(256) void k2_kv(const float* __restrict__ nodes,
                                             const float* __restrict__ Wk,
                                             const float* __restrict__ Wv,
                                             __fp16* __restrict__ Kf,
                                             __fp16* __restrict__ Vf) {
    __shared__ __fp16 wt[128 * 132];   // W^T[n][k]
    const int tid = threadIdx.x;
    const int b = blockIdx.y;
    const int kv = blockIdx.z;
    const float* W = (kv == 0) ? Wk : Wv;
    for (int i = tid; i < 128 * 128; i += 256) {
        int k = i >> 7, n = i & 127;
        wt[n * 132 + k] = (__fp16)W[i];
    }
    __syncthreads();

    const int wid = tid >> 6, lane = tid & 63;
    const int lp = lane & 15, lg = lane >> 4;
    const int nb = blockIdx.x * 64 + wid * 16;   // 16 x-blocks -> rows 0..1023

    int nr = nb + lp;
    if (nr >= NN) nr = NN - 1;                   // clamp; garbage zeroed on store
    const float* arow = nodes + (size_t)(b * NN + nr) * 128;

    v4f acc[8];
#pragma unroll
    for (int cf = 0; cf < 8; cf++) acc[cf] = (v4f){0.f, 0.f, 0.f, 0.f};

#pragma unroll
    for (int k0 = 0; k0 < 8; k0++) {
        float4 av = *(const float4*)&arow[k0 * 16 + 4 * lg];
        v4h af;
        af[0] = (__fp16)av.x; af[1] = (__fp16)av.y;
        af[2] = (__fp16)av.z; af[3] = (__fp16)av.w;
#pragma unroll
        for (int cf = 0; cf < 8; cf++) {
            v4h bf = *(const v4h*)&wt[(cf * 16 + lp) * 132 + k0 * 16 + 4 * lg];
            acc[cf] = __builtin_amdgcn_mfma_f32_16x16x16f16(af, bf, acc[cf], 0, 0, 0);
        }
    }

    if (kv == 0) {
        // col = h*16 + d: cf = h, lp = d.  Kf[b,h,n,d], n = nb + 4*lg + r
#pragma unroll
        for (int cf = 0; cf < 8; cf++) {
            const size_t base = ((size_t)(b * HH + cf) << 14) + lp;
#pragma unroll
            for (int r = 0; r < 4; r++) {
                const int n = nb + 4 * lg + r;
                Kf[base + (size_t)n * 16] = (n < NN) ? (__fp16)acc[cf][r] : (__fp16)0.f;
            }
        }
    } else {
        // Vf[b,h,d,n]: cf = h, lp = d, n = nb + 4*lg + r (4 consecutive -> v4h)
#pragma unroll
        for (int cf = 0; cf < 8; cf++) {
            v4h pk;
#pragma unroll
            for (int r = 0; r < 4; r++) {
                const int n = nb + 4 * lg + r;
                pk[r] = (n < NN) ? (__fp16)acc[cf][r] : (__fp16)0.f;
            }
            *(v4h*)&Vf[(((size_t)(b * HH + cf) * 16 + lp) << 10) + nb + 4 * lg] = pk;
        }
    }
}

// ---------------------------------------------------------------------------
// k3: MFMA attention, zero LDS.
// R8: head-split.  R6 structure (full 62-step K-loop, fp32 Aout, no combine)
// but 2 head-chains/wave instead of 4 -> grid 1024 = 4 blocks/CU = 16 waves/CU.
// Write volume identical to R6 (fp32, 128B contiguous per row per block).
// ---------------------------------------------------------------------------
__global__ __launch_bounds__(256) void k3_attn(const __fp16* __restrict__ Qh,
                                               const __fp16* __restrict__ Kf,
                                               const __fp16* __restrict__ Vf,
                                               const float* __restrict__ mask,
                                               float* __restrict__ Aout) {
    const int tid = threadIdx.x;
    const int bid = blockIdx.x;            // 1024
    const int b = bid & 63;                // bid&7 = b&7 -> XCD locality on b
    const int c = bid >> 6;                // 0..15
    const int hg = c & 3, pt = c >> 2;
    const int h0 = hg * 2;
    const int p0 = pt * 64;

    const int wid = tid >> 6, lane = tid & 63;
    const int lp = lane & 15, lg = lane >> 4;
    const int pw = p0 + wid * 16;

    v4h qf[2];
    {
        const __fp16* qrow = Qh + (size_t)(b * PP + pw + lp) * 128 + h0 * 16 + 4 * lg;
#pragma unroll
        for (int j = 0; j < 2; j++) qf[j] = *(const v4h*)&qrow[j * 16];
    }

    v4f acc[2];
    float lsum[2];
#pragma unroll
    for (int j = 0; j < 2; j++) { acc[j] = (v4f){0.f, 0.f, 0.f, 0.f}; lsum[j] = 0.f; }
    const v4f zero4 = {0.f, 0.f, 0.f, 0.f};

    const __fp16* kp = Kf + ((size_t)(b * HH + h0) << 14);          // [h][n][16]
    const __fp16* vp = Vf + ((size_t)((b * HH + h0) * 16) << 10);   // [h][d][NP]
    const float* mrow = mask + (size_t)(b * PP + pw + lp) * NN;

#pragma unroll 2
    for (int s = 0; s < 62; s++) {
        const int nl = s * 16;
        v4h kf[2], vf[2];
#pragma unroll
        for (int j = 0; j < 2; j++)
            kf[j] = *(const v4h*)&kp[(j << 14) + (nl + lp) * 16 + 4 * lg];
#pragma unroll
        for (int j = 0; j < 2; j++)
            vf[j] = *(const v4h*)&vp[(j << 14) + lp * NP + nl + 4 * lg];
        float4 mv = *(const float4*)&mrow[nl + 4 * lg];
#pragma unroll
        for (int j = 0; j < 2; j++) {
            v4f sc = __builtin_amdgcn_mfma_f32_16x16x16f16(kf[j], qf[j], zero4, 0, 0, 0);
            float w0 = __expf(sc[0] + mv.x);
            float w1 = __expf(sc[1] + mv.y);
            float w2 = __expf(sc[2] + mv.z);
            float w3 = __expf(sc[3] + mv.w);
            lsum[j] += (w0 + w1) + (w2 + w3);
            v4h wf;
            wf[0] = (__fp16)w0; wf[1] = (__fp16)w1; wf[2] = (__fp16)w2; wf[3] = (__fp16)w3;
            acc[j] = __builtin_amdgcn_mfma_f32_16x16x16f16(wf, vf[j], acc[j], 0, 0, 0);
        }
    }
    {   // tail step: n = 992 + 4*lg + r
        const int nl = 992;
        int nc = nl + 4 * lg; if (nc > 996) nc = 996;
        float4 mv = *(const float4*)&mrow[nc];
        const bool b0 = (nl + 4 * lg + 0 < NN), b1 = (nl + 4 * lg + 1 < NN);
        const bool b2 = (nl + 4 * lg + 2 < NN), b3 = (nl + 4 * lg + 3 < NN);
#pragma unroll
        for (int j = 0; j < 2; j++) {
            v4h kf = *(const v4h*)&kp[(j << 14) + (nl + lp) * 16 + 4 * lg];
            v4h vf = *(const v4h*)&vp[(j << 14) + lp * NP + nl + 4 * lg];
            v4f sc = __builtin_amdgcn_mfma_f32_16x16x16f16(kf, qf[j], zero4, 0, 0, 0);
            float w0 = b0 ? __expf(sc[0] + mv.x) : 0.f;
            float w1 = b1 ? __expf(sc[1] + mv.y) : 0.f;
            float w2 = b2 ? __expf(sc[2] + mv.z) : 0.f;
            float w3 = b3 ? __expf(sc[3] + mv.w) : 0.f;
            lsum[j] += (w0 + w1) + (w2 + w3);
            v4h wf;
            wf[0] = (__fp16)w0; wf[1] = (__fp16)w1; wf[2] = (__fp16)w2; wf[3] = (__fp16)w3;
            acc[j] = __builtin_amdgcn_mfma_f32_16x16x16f16(wf, vf, acc[j], 0, 0, 0);
        }
    }

#pragma unroll
    for (int j = 0; j < 2; j++) {
        float l = lsum[j];
        l += __shfl_xor(l, 16);
        l += __shfl_xor(l, 32);
#pragma unroll
        for (int r = 0; r < 4; r++) {
            float denom = __shfl(l, 4 * lg + r);
            float inv = 1.f / denom;
            Aout[(size_t)(b * PP + pw + 4 * lg + r) * 128 + (h0 + j) * 16 + lp] =
                acc[j][r] * inv;
        }
    }
}

// ---------------------------------------------------------------------------
// k4: mh MFMA.  Mh_h = fp16( (Aout @ Wo + bo) * (1/sqrt(128)) )
// ---------------------------------------------------------------------------
__global__ __launch_bounds__(256) void k4_mh(const float* __restrict__ Ain,
                                             const float* __restrict__ Wo,
                                             const float* __restrict__ bo,
                                             __fp16* __restrict__ Mh) {
    __shared__ __fp16 wt[128 * 132];   // Wo^T[n][k]
    const int tid = threadIdx.x;
    const int row0 = blockIdx.x * 64;
    for (int i = tid; i < 128 * 128; i += 256) {
        int k = i >> 7, n = i & 127;
        wt[n * 132 + k] = (__fp16)Wo[i];
    }
    __syncthreads();

    const int wid = tid >> 6, lane = tid & 63;
    const int lp = lane & 15, lg = lane >> 4;
    const int rb = row0 + wid * 16;

    const float* arow = Ain + (size_t)(rb + lp) * 128;
    v4f acc[8];
#pragma unroll
    for (int cf = 0; cf < 8; cf++) acc[cf] = (v4f){0.f, 0.f, 0.f, 0.f};

#pragma unroll
    for (int k0 = 0; k0 < 8; k0++) {
        float4 av = *(const float4*)&arow[k0 * 16 + 4 * lg];
        v4h af;
        af[0] = (__fp16)av.x; af[1] = (__fp16)av.y;
        af[2] = (__fp16)av.z; af[3] = (__fp16)av.w;
#pragma unroll
        for (int cf = 0; cf < 8; cf++) {
            v4h bf = *(const v4h*)&wt[(cf * 16 + lp) * 132 + k0 * 16 + 4 * lg];
            acc[cf] = __builtin_amdgcn_mfma_f32_16x16x16f16(af, bf, acc[cf], 0, 0, 0);
        }
    }

    const float scale = 0.08838834764831845f;   // 1/sqrt(128)
#pragma unroll
    for (int cf = 0; cf < 8; cf++) {
        const int col = cf * 16 + lp;
        const float bb = bo[col];
#pragma unroll
        for (int r = 0; r < 4; r++) {
            const int rl = wid * 16 + 4 * lg + r;
            Mh[(size_t)(row0 + rl) * 128 + col] = (__fp16)((acc[cf][r] + bb) * scale);
        }
    }
}

// ---------------------------------------------------------------------------
// k5: final scoring + tanh-clip softmax (R4 structure; mh fp16 pre-scaled)
// ---------------------------------------------------------------------------
__global__ __launch_bounds__(256) void k5_final(const float* __restrict__ nodes,
                                                const __fp16* __restrict__ Mh,
                                                const float* __restrict__ mask,
                                                float* __restrict__ out) {
    __shared__ __fp16 probs[16 * 1028];
    __shared__ float rowsum[16];
    __shared__ float rowinv[16];
    const int tid = threadIdx.x;
    const int bid = blockIdx.x;          // 1024 = 64 b x 16 pt, XCD-swizzled
    const int xcd = bid & 7;
    const int rest = bid >> 3;
    const int pt = rest & 15;
    const int b = ((rest >> 4) << 3) + xcd;
    const int p0 = pt * 16;

    if (tid < 16) rowsum[tid] = 0.f;

    const int wid = tid >> 6, lane = tid & 63;
    const int lp = lane & 15, lg = lane >> 4;

    v4h bf[8];
    {
        const __fp16* mhrow = Mh + (size_t)(b * PP + p0 + lp) * 128;
#pragma unroll
        for (int ec = 0; ec < 8; ec++)
            bf[ec] = *(const v4h*)&mhrow[ec * 16 + 4 * lg];
    }
    __syncthreads();

    float lsum = 0.f;
    const float* nbase = nodes + (size_t)b * NN * 128;
    const float* mkrow = mask + (size_t)(b * PP + p0 + lp) * NN;
    const v4f zero4 = {0.f, 0.f, 0.f, 0.f};

    for (int s = 0; s < 16; s++) {
        const int nt = s * 64 + wid * 16;
        int nr = nt + lp;
        if (nr >= NN) nr = NN - 1;
        const float* arow = nbase + (size_t)nr * 128;
        v4f acc = zero4;
#pragma unroll
        for (int ec = 0; ec < 8; ec++) {
            float4 av = *(const float4*)&arow[ec * 16 + 4 * lg];
            v4h af;
            af[0] = (__fp16)av.x; af[1] = (__fp16)av.y;
            af[2] = (__fp16)av.z; af[3] = (__fp16)av.w;
            acc = __builtin_amdgcn_mfma_f32_16x16x16f16(af, bf[ec], acc, 0, 0, 0);
        }
        const int nb4 = nt + 4 * lg;
        v4h wf;
        if (nt + 15 < NN) {
            float4 mkv = *(const float4*)&mkrow[nb4];
            float e0 = __expf(2.f * acc[0]);
            float e1 = __expf(2.f * acc[1]);
            float e2 = __expf(2.f * acc[2]);
            float e3 = __expf(2.f * acc[3]);
            float w0 = __expf(fmaf(-20.f, __builtin_amdgcn_rcpf(e0 + 1.f), mkv.x));
            float w1 = __expf(fmaf(-20.f, __builtin_amdgcn_rcpf(e1 + 1.f), mkv.y));
            float w2 = __expf(fmaf(-20.f, __builtin_amdgcn_rcpf(e2 + 1.f), mkv.z));
            float w3 = __expf(fmaf(-20.f, __builtin_amdgcn_rcpf(e3 + 1.f), mkv.w));
            lsum += (w0 + w1) + (w2 + w3);
            wf[0] = (__fp16)w0; wf[1] = (__fp16)w1; wf[2] = (__fp16)w2; wf[3] = (__fp16)w3;
        } else {
            float w[4];
#pragma unroll
            for (int r = 0; r < 4; r++) {
                if (nb4 + r < NN) {
                    float e = __expf(2.f * acc[r]);
                    w[r] = __expf(fmaf(-20.f, __builtin_amdgcn_rcpf(e + 1.f),
                                       mkrow[nb4 + r]));
                } else {
                    w[r] = 0.f;
                }
            }
            lsum += (w[0] + w[1]) + (w[2] + w[3]);
            wf[0] = (__fp16)w[0]; wf[1] = (__fp16)w[1];
            wf[2] = (__fp16)w[2]; wf[3] = (__fp16)w[3];
        }
        *(v4h*)&probs[lp * 1028 + nb4] = wf;
    }

    lsum += __shfl_xor(lsum, 16);
    lsum += __shfl_xor(lsum, 32);
    if (lane < 16) atomicAdd(&rowsum[lane], lsum);
    __syncthreads();
    if (tid < 16) rowinv[tid] = 1.f / rowsum[tid];
    __syncthreads();

    if (tid < 250) {
        const int c4 = tid * 4;
        const size_t obase = (size_t)(b * PP + p0) * NN;
#pragma unroll 4
        for (int r = 0; r < 16; r++) {
            v4h pv = *(const v4h*)&probs[r * 1028 + c4];
            float inv = rowinv[r];
            float4 ov;
            ov.x = (float)pv[0] * inv;
            ov.y = (float)pv[1] * inv;
            ov.z = (float)pv[2] * inv;
            ov.w = (float)pv[3] * inv;
            *(float4*)&out[obase + (size_t)r * NN + c4] = ov;
        }
    }
}

extern "C" void kernel_launch(void* const* d_in, const int* in_sizes, int n_in,
                              void* d_out, int out_size, void* d_ws, size_t ws_size,
                              hipStream_t stream) {
    const float* nodes = (const float*)d_in[0];
    const float* ln    = (const float*)d_in[1];
    const float* attr  = (const float*)d_in[2];
    const float* mask  = (const float*)d_in[3];
    const float* Wq    = (const float*)d_in[4];
    const float* Wk    = (const float*)d_in[5];
    const float* Wv    = (const float*)d_in[6];
    const float* Wo    = (const float*)d_in[7];
    const float* bo    = (const float*)d_in[8];
    float* out = (float*)d_out;

    // workspace layout (floats): Aout fp32 [16384*128], then fp16 Qh, Mh
    float*  Aout = (float*)d_ws;                       // 2,097,152 floats
    __fp16* Qh   = (__fp16*)(Aout + 2097152);          // 2,097,152 halfs
    __fp16* Mhh  = Qh + 2097152;                       // 2,097,152 halfs

    // d_out doubles as fp16 K/V scratch (fully rewritten every launch)
    __fp16* Kf = (__fp16*)d_out;
    __fp16* Vf = Kf + (size_t)BB * HH * NP * 16;

    hipLaunchKernelGGL(k1_qproj, dim3(256), dim3(256), 0, stream, ln, attr, Wq, Qh);
    hipLaunchKernelGGL(k2_kv, dim3(16, 64, 2), dim3(256), 0, stream, nodes, Wk, Wv, Kf, Vf);
    hipLaunchKernelGGL(k3_attn, dim3(1024), dim3(256), 0, stream, Qh, Kf, Vf, mask, Aout);
    hipLaunchKernelGGL(k4_mh, dim3(256), dim3(256), 0, stream, Aout, Wo, bo, Mhh);
    hipLaunchKernelGGL(k5_final, dim3(1024), dim3(256), 0, stream, nodes, Mhh, mask, out);
}

// Round 5
// 302.135 us; speedup vs baseline: 1.2011x; 1.1210x over previous
//
#include <hip/hip_runtime.h>

#define BB 64
#define PP 256
#define NN 1000
#define NP 1024   // padded KV rows (power of 2, zero-filled beyond NN)
#define EE 128
#define HH 8
#define DD 16
// H*D = 128

typedef __fp16 v4h __attribute__((ext_vector_type(4)));
typedef float v4f __attribute__((ext_vector_type(4)));

// Shared MFMA GEMM convention (validated in k3/k5 since R2):
//   af = X[m = lane&15][k = 4*(lane>>4)+j]      (v4h)
//   bf = W^T[n = lane&15][k = 4*(lane>>4)+j]    (v4h, from LDS)
//   D  = mfma(af, bf, acc):  acc[r] = C[m = 4*(lane>>4)+r][n = lane&15]

// ---------------------------------------------------------------------------
// k1: Q projection, MFMA.  Qh = 0.25 * (concat(ln, attr) @ Wq), fp16 out.
// attr (K-row 128) applied as rank-1 epilogue update.
// ---------------------------------------------------------------------------
__global__ __launch_bounds__(256) void k1_qproj(const float* __restrict__ ln,
                                                const float* __restrict__ attr,
                                                const float* __restrict__ Wq,
                                                __fp16* __restrict__ Qh) {
    __shared__ __fp16 wt[128 * 132];   // Wq^T[n][k], first 128 k-rows
    __shared__ float attrs[64];
    const int tid = threadIdx.x;
    const int row0 = blockIdx.x * 64;   // 256 blocks
    for (int i = tid; i < 128 * 128; i += 256) {
        int k = i >> 7, n = i & 127;
        wt[n * 132 + k] = (__fp16)Wq[i];
    }
    if (tid < 64) attrs[tid] = attr[row0 + tid];
    __syncthreads();

    const int wid = tid >> 6, lane = tid & 63;
    const int lp = lane & 15, lg = lane >> 4;
    const int rb = row0 + wid * 16;

    const float* arow = ln + (size_t)(rb + lp) * 128;
    v4f acc[8];
#pragma unroll
    for (int cf = 0; cf < 8; cf++) acc[cf] = (v4f){0.f, 0.f, 0.f, 0.f};

#pragma unroll
    for (int k0 = 0; k0 < 8; k0++) {
        float4 av = *(const float4*)&arow[k0 * 16 + 4 * lg];
        v4h af;
        af[0] = (__fp16)av.x; af[1] = (__fp16)av.y;
        af[2] = (__fp16)av.z; af[3] = (__fp16)av.w;
#pragma unroll
        for (int cf = 0; cf < 8; cf++) {
            v4h bf = *(const v4h*)&wt[(cf * 16 + lp) * 132 + k0 * 16 + 4 * lg];
            acc[cf] = __builtin_amdgcn_mfma_f32_16x16x16f16(af, bf, acc[cf], 0, 0, 0);
        }
    }

#pragma unroll
    for (int cf = 0; cf < 8; cf++) {
        const int col = cf * 16 + lp;
        const float w128 = Wq[128 * 128 + col];
#pragma unroll
        for (int r = 0; r < 4; r++) {
            const int rl = wid * 16 + 4 * lg + r;
            float v = (acc[cf][r] + attrs[rl] * w128) * 0.25f;
            Qh[(size_t)(row0 + rl) * 128 + col] = (__fp16)v;
        }
    }
}

// ---------------------------------------------------------------------------
// k2: K/V projection, MFMA.  blockIdx.z: 0 -> Kf [B,H,NP,16], 1 -> Vt tiled.
// Vt layout: [b,h, tile=n>>4, d, n&15] — each 16x16 V^T tile is 512 B dense,
// so k3's staging load of one tile touches 8 cachelines instead of 16.
// Rows padded to NP=1024, zero-filled beyond NN.
// ---------------------------------------------------------------------------
__global__ __launch_bounds__(256) void k2_kv(const float* __restrict__ nodes,
                                             const float* __restrict__ Wk,
                                             const float* __restrict__ Wv,
                                             __fp16* __restrict__ Kf,
                                             __fp16* __restrict__ Vt) {
    __shared__ __fp16 wt[128 * 132];   // W^T[n][k]
    const int tid = threadIdx.x;
    const int b = blockIdx.y;
    const int kv = blockIdx.z;
    const float* W = (kv == 0) ? Wk : Wv;
    for (int i = tid; i < 128 * 128; i += 256) {
        int k = i >> 7, n = i & 127;
        wt[n * 132 + k] = (__fp16)W[i];
    }
    __syncthreads();

    const int wid = tid >> 6, lane = tid & 63;
    const int lp = lane & 15, lg = lane >> 4;
    const int nb = blockIdx.x * 64 + wid * 16;   // 16 x-blocks -> rows 0..1023

    int nr = nb + lp;
    if (nr >= NN) nr = NN - 1;                   // clamp; garbage zeroed on store
    const float* arow = nodes + (size_t)(b * NN + nr) * 128;

    v4f acc[8];
#pragma unroll
    for (int cf = 0; cf < 8; cf++) acc[cf] = (v4f){0.f, 0.f, 0.f, 0.f};

#pragma unroll
    for (int k0 = 0; k0 < 8; k0++) {
        float4 av = *(const float4*)&arow[k0 * 16 + 4 * lg];
        v4h af;
        af[0] = (__fp16)av.x; af[1] = (__fp16)av.y;
        af[2] = (__fp16)av.z; af[3] = (__fp16)av.w;
#pragma unroll
        for (int cf = 0; cf < 8; cf++) {
            v4h bf = *(const v4h*)&wt[(cf * 16 + lp) * 132 + k0 * 16 + 4 * lg];
            acc[cf] = __builtin_amdgcn_mfma_f32_16x16x16f16(af, bf, acc[cf], 0, 0, 0);
        }
    }

    if (kv == 0) {
        // col = h*16 + d: cf = h, lp = d.  Kf[b,h,n,d], n = nb + 4*lg + r
#pragma unroll
        for (int cf = 0; cf < 8; cf++) {
            const size_t base = ((size_t)(b * HH + cf) << 14) + lp;
#pragma unroll
            for (int r = 0; r < 4; r++) {
                const int n = nb + 4 * lg + r;
                Kf[base + (size_t)n * 16] = (n < NN) ? (__fp16)acc[cf][r] : (__fp16)0.f;
            }
        }
    } else {
        // Vt[b,h,tile][d=lp][n&15 = 4*lg+r] (4 consecutive -> v4h)
#pragma unroll
        for (int cf = 0; cf < 8; cf++) {
            v4h pk;
#pragma unroll
            for (int r = 0; r < 4; r++) {
                const int n = nb + 4 * lg + r;
                pk[r] = (n < NN) ? (__fp16)acc[cf][r] : (__fp16)0.f;
            }
            *(v4h*)&Vt[((size_t)(b * HH + cf) << 14) + (size_t)(nb >> 4) * 256 +
                       lp * 16 + 4 * lg] = pk;
        }
    }
}

// ---------------------------------------------------------------------------
// k3: MFMA attention.  R9: LDS-staged K/V (double-buffered), 2 head-chains/wave,
// grid 1024 (4 blocks/CU).  Wave w cooperatively stages chunk w (K h0, K h1,
// V h0, V h1: 512 B tiles) once per step -> global line-touches per wave-step
// drop ~64 -> ~24.  Mask + stage loads prefetched one step ahead (ping-pong
// regs, unroll-2 keeps indices static).  Numerics identical to R6/R8.
// ---------------------------------------------------------------------------
__global__ __launch_bounds__(256) void k3_attn(const __fp16* __restrict__ Qh,
                                               const __fp16* __restrict__ Kf,
                                               const __fp16* __restrict__ Vt,
                                               const float* __restrict__ mask,
                                               float* __restrict__ Aout) {
    __shared__ __fp16 sh[2][4][256];   // [buf][chunk: Kh0,Kh1,Vh0,Vh1][16x16 tile]
    const int tid = threadIdx.x;
    const int bid = blockIdx.x;            // 1024
    const int b = bid & 63;                // bid&7 = b&7 -> XCD locality on b
    const int rest = bid >> 6;             // 0..15
    const int hg = rest & 3, pt = rest >> 2;
    const int h0 = hg * 2;
    const int p0 = pt * 64;

    const int wid = tid >> 6, lane = tid & 63;
    const int lp = lane & 15, lg = lane >> 4;
    const int pw = p0 + wid * 16;

    // staging source: wave w handles chunk w
    const __fp16* gsrc = ((wid < 2) ? Kf + ((size_t)(b * HH + h0 + wid) << 14)
                                    : Vt + ((size_t)(b * HH + h0 + wid - 2) << 14)) +
                         lane * 4;
    __fp16* sdst0 = &sh[0][wid][lane * 4];
    __fp16* sdst1 = &sh[1][wid][lane * 4];

    v4h qf[2];
    {
        const __fp16* qrow = Qh + (size_t)(b * PP + pw + lp) * 128 + h0 * 16 + 4 * lg;
        qf[0] = *(const v4h*)&qrow[0];
        qf[1] = *(const v4h*)&qrow[16];
    }

    const float* mrow = mask + (size_t)(b * PP + pw + lp) * NN;

    v4f acc[2];
    float lsum[2];
    acc[0] = (v4f){0.f, 0.f, 0.f, 0.f};
    acc[1] = (v4f){0.f, 0.f, 0.f, 0.f};
    lsum[0] = 0.f; lsum[1] = 0.f;
    const v4f zero4 = {0.f, 0.f, 0.f, 0.f};

    // prologue: stage tile 0 into buf0; preload tile-1 regs and mask(0)
    v4h st[2];
    float4 mv[2];
    st[0] = *(const v4h*)(gsrc);            // tile 0
    *(v4h*)sdst0 = st[0];
    st[1] = *(const v4h*)(gsrc + 256);      // tile 1 (written to buf1 in iter 0)
    mv[0] = *(const float4*)&mrow[4 * lg];  // mask step 0
    __syncthreads();

    // invariants at top of iter s: sh[s&1] holds tile s; st[(s+1)&1] holds
    // tile s+1; mv[s&1] holds mask(s).
#pragma unroll 2
    for (int s = 0; s < 62; s++) {
        const int p = s & 1;
        // prefetch: tile s+2 regs, mask s+1
        if (s + 2 <= 62) st[p] = *(const v4h*)(gsrc + (s + 2) * 256);
        {
            int moff = (s + 1) * 16 + 4 * lg;
            if (moff > 996) moff = 996;     // only clamps at s+1 == 62
            mv[p ^ 1] = *(const float4*)&mrow[moff];
        }

        // compute step s from sh[p]
        v4h kf0 = *(const v4h*)&sh[p][0][lp * 16 + 4 * lg];
        v4h kf1 = *(const v4h*)&sh[p][1][lp * 16 + 4 * lg];
        v4h vf0 = *(const v4h*)&sh[p][2][lp * 16 + 4 * lg];
        v4h vf1 = *(const v4h*)&sh[p][3][lp * 16 + 4 * lg];
        const float4 m = mv[p];
        {
            v4f sc = __builtin_amdgcn_mfma_f32_16x16x16f16(kf0, qf[0], zero4, 0, 0, 0);
            float w0 = __expf(sc[0] + m.x);
            float w1 = __expf(sc[1] + m.y);
            float w2 = __expf(sc[2] + m.z);
            float w3 = __expf(sc[3] + m.w);
            lsum[0] += (w0 + w1) + (w2 + w3);
            v4h wf;
            wf[0] = (__fp16)w0; wf[1] = (__fp16)w1; wf[2] = (__fp16)w2; wf[3] = (__fp16)w3;
            acc[0] = __builtin_amdgcn_mfma_f32_16x16x16f16(wf, vf0, acc[0], 0, 0, 0);
        }
        {
            v4f sc = __builtin_amdgcn_mfma_f32_16x16x16f16(kf1, qf[1], zero4, 0, 0, 0);
            float w0 = __expf(sc[0] + m.x);
            float w1 = __expf(sc[1] + m.y);
            float w2 = __expf(sc[2] + m.z);
            float w3 = __expf(sc[3] + m.w);
            lsum[1] += (w0 + w1) + (w2 + w3);
            v4h wf;
            wf[0] = (__fp16)w0; wf[1] = (__fp16)w1; wf[2] = (__fp16)w2; wf[3] = (__fp16)w3;
            acc[1] = __builtin_amdgcn_mfma_f32_16x16x16f16(wf, vf1, acc[1], 0, 0, 0);
        }

        // publish tile s+1 into the other buffer (safe: all waves finished
        // reading it in iter s-1 before the barrier below)
        *(v4h*)((p == 0) ? sdst1 : sdst0) = st[p ^ 1];
        __syncthreads();
    }

    {   // tail step s=62 (parity 0): n = 992 + 4*lg + r, bounds-guarded
        const int nl = 992;
        const float4 m = mv[0];
        const bool c0 = (nl + 4 * lg + 0 < NN), c1 = (nl + 4 * lg + 1 < NN);
        const bool c2 = (nl + 4 * lg + 2 < NN), c3 = (nl + 4 * lg + 3 < NN);
        v4h kf0 = *(const v4h*)&sh[0][0][lp * 16 + 4 * lg];
        v4h kf1 = *(const v4h*)&sh[0][1][lp * 16 + 4 * lg];
        v4h vf0 = *(const v4h*)&sh[0][2][lp * 16 + 4 * lg];
        v4h vf1 = *(const v4h*)&sh[0][3][lp * 16 + 4 * lg];
        {
            v4f sc = __builtin_amdgcn_mfma_f32_16x16x16f16(kf0, qf[0], zero4, 0, 0, 0);
            float w0 = c0 ? __expf(sc[0] + m.x) : 0.f;
            float w1 = c1 ? __expf(sc[1] + m.y) : 0.f;
            float w2 = c2 ? __expf(sc[2] + m.z) : 0.f;
            float w3 = c3 ? __expf(sc[3] + m.w) : 0.f;
            lsum[0] += (w0 + w1) + (w2 + w3);
            v4h wf;
            wf[0] = (__fp16)w0; wf[1] = (__fp16)w1; wf[2] = (__fp16)w2; wf[3] = (__fp16)w3;
            acc[0] = __builtin_amdgcn_mfma_f32_16x16x16f16(wf, vf0, acc[0], 0, 0, 0);
        }
        {
            v4f sc = __builtin_amdgcn_mfma_f32_16x16x16f16(kf1, qf[1], zero4, 0, 0, 0);
            float w0 = c0 ? __expf(sc[0] + m.x) : 0.f;
            float w1 = c1 ? __expf(sc[1] + m.y) : 0.f;
            float w2 = c2 ? __expf(sc[2] + m.z) : 0.f;
            float w3 = c3 ? __expf(sc[3] + m.w) : 0.f;
            lsum[1] += (w0 + w1) + (w2 + w3);
            v4h wf;
            wf[0] = (__fp16)w0; wf[1] = (__fp16)w1; wf[2] = (__fp16)w2; wf[3] = (__fp16)w3;
            acc[1] = __builtin_amdgcn_mfma_f32_16x16x16f16(wf, vf1, acc[1], 0, 0, 0);
        }
    }

#pragma unroll
    for (int j = 0; j < 2; j++) {
        float l = lsum[j];
        l += __shfl_xor(l, 16);
        l += __shfl_xor(l, 32);
#pragma unroll
        for (int r = 0; r < 4; r++) {
            float denom = __shfl(l, 4 * lg + r);
            float inv = 1.f / denom;
            Aout[(size_t)(b * PP + pw + 4 * lg + r) * 128 + (h0 + j) * 16 + lp] =
                acc[j][r] * inv;
        }
    }
}

// ---------------------------------------------------------------------------
// k4: mh MFMA.  Mh_h = fp16( (Aout @ Wo + bo) * (1/sqrt(128)) )
// ---------------------------------------------------------------------------
__global__ __launch_bounds__(256) void k4_mh(const float* __restrict__ Ain,
                                             const float* __restrict__ Wo,
                                             const float* __restrict__ bo,
                                             __fp16* __restrict__ Mh) {
    __shared__ __fp16 wt[128 * 132];   // Wo^T[n][k]
    const int tid = threadIdx.x;
    const int row0 = blockIdx.x * 64;
    for (int i = tid; i < 128 * 128; i += 256) {
        int k = i >> 7, n = i & 127;
        wt[n * 132 + k] = (__fp16)Wo[i];
    }
    __syncthreads();

    const int wid = tid >> 6, lane = tid & 63;
    const int lp = lane & 15, lg = lane >> 4;
    const int rb = row0 + wid * 16;

    const float* arow = Ain + (size_t)(rb + lp) * 128;
    v4f acc[8];
#pragma unroll
    for (int cf = 0; cf < 8; cf++) acc[cf] = (v4f){0.f, 0.f, 0.f, 0.f};

#pragma unroll
    for (int k0 = 0; k0 < 8; k0++) {
        float4 av = *(const float4*)&arow[k0 * 16 + 4 * lg];
        v4h af;
        af[0] = (__fp16)av.x; af[1] = (__fp16)av.y;
        af[2] = (__fp16)av.z; af[3] = (__fp16)av.w;
#pragma unroll
        for (int cf = 0; cf < 8; cf++) {
            v4h bf = *(const v4h*)&wt[(cf * 16 + lp) * 132 + k0 * 16 + 4 * lg];
            acc[cf] = __builtin_amdgcn_mfma_f32_16x16x16f16(af, bf, acc[cf], 0, 0, 0);
        }
    }

    const float scale = 0.08838834764831845f;   // 1/sqrt(128)
#pragma unroll
    for (int cf = 0; cf < 8; cf++) {
        const int col = cf * 16 + lp;
        const float bb = bo[col];
#pragma unroll
        for (int r = 0; r < 4; r++) {
            const int rl = wid * 16 + 4 * lg + r;
            Mh[(size_t)(row0 + rl) * 128 + col] = (__fp16)((acc[cf][r] + bb) * scale);
        }
    }
}

// ---------------------------------------------------------------------------
// k5: final scoring + tanh-clip softmax (R4 structure; mh fp16 pre-scaled)
// ---------------------------------------------------------------------------
__global__ __launch_bounds__(256) void k5_final(const float* __restrict__ nodes,
                                                const __fp16* __restrict__ Mh,
                                                const float* __restrict__ mask,
                                                float* __restrict__ out) {
    __shared__ __fp16 probs[16 * 1028];
    __shared__ float rowsum[16];
    __shared__ float rowinv[16];
    const int tid = threadIdx.x;
    const int bid = blockIdx.x;          // 1024 = 64 b x 16 pt, XCD-swizzled
    const int xcd = bid & 7;
    const int rest = bid >> 3;
    const int pt = rest & 15;
    const int b = ((rest >> 4) << 3) + xcd;
    const int p0 = pt * 16;

    if (tid < 16) rowsum[tid] = 0.f;

    const int wid = tid >> 6, lane = tid & 63;
    const int lp = lane & 15, lg = lane >> 4;

    v4h bf[8];
    {
        const __fp16* mhrow = Mh + (size_t)(b * PP + p0 + lp) * 128;
#pragma unroll
        for (int ec = 0; ec < 8; ec++)
            bf[ec] = *(const v4h*)&mhrow[ec * 16 + 4 * lg];
    }
    __syncthreads();

    float lsum = 0.f;
    const float* nbase = nodes + (size_t)b * NN * 128;
    const float* mkrow = mask + (size_t)(b * PP + p0 + lp) * NN;
    const v4f zero4 = {0.f, 0.f, 0.f, 0.f};

    for (int s = 0; s < 16; s++) {
        const int nt = s * 64 + wid * 16;
        int nr = nt + lp;
        if (nr >= NN) nr = NN - 1;
        const float* arow = nbase + (size_t)nr * 128;
        v4f acc = zero4;
#pragma unroll
        for (int ec = 0; ec < 8; ec++) {
            float4 av = *(const float4*)&arow[ec * 16 + 4 * lg];
            v4h af;
            af[0] = (__fp16)av.x; af[1] = (__fp16)av.y;
            af[2] = (__fp16)av.z; af[3] = (__fp16)av.w;
            acc = __builtin_amdgcn_mfma_f32_16x16x16f16(af, bf[ec], acc, 0, 0, 0);
        }
        const int nb4 = nt + 4 * lg;
        v4h wf;
        if (nt + 15 < NN) {
            float4 mkv = *(const float4*)&mkrow[nb4];
            float e0 = __expf(2.f * acc[0]);
            float e1 = __expf(2.f * acc[1]);
            float e2 = __expf(2.f * acc[2]);
            float e3 = __expf(2.f * acc[3]);
            float w0 = __expf(fmaf(-20.f, __builtin_amdgcn_rcpf(e0 + 1.f), mkv.x));
            float w1 = __expf(fmaf(-20.f, __builtin_amdgcn_rcpf(e1 + 1.f), mkv.y));
            float w2 = __expf(fmaf(-20.f, __builtin_amdgcn_rcpf(e2 + 1.f), mkv.z));
            float w3 = __expf(fmaf(-20.f, __builtin_amdgcn_rcpf(e3 + 1.f), mkv.w));
            lsum += (w0 + w1) + (w2 + w3);
            wf[0] = (__fp16)w0; wf[1] = (__fp16)w1; wf[2] = (__fp16)w2; wf[3] = (__fp16)w3;
        } else {
            float w[4];
#pragma unroll
            for (int r = 0; r < 4; r++) {
                if (nb4 + r < NN) {
                    float e = __expf(2.f * acc[r]);
                    w[r] = __expf(fmaf(-20.f, __builtin_amdgcn_rcpf(e + 1.f),
                                       mkrow[nb4 + r]));
                } else {
                    w[r] = 0.f;
                }
            }
            lsum += (w[0] + w[1]) + (w[2] + w[3]);
            wf[0] = (__fp16)w[0]; wf[1] = (__fp16)w[1];
            wf[2] = (__fp16)w[2]; wf[3] = (__fp16)w[3];
        }
        *(v4h*)&probs[lp * 1028 + nb4] = wf;
    }

    lsum += __shfl_xor(lsum, 16);
    lsum += __shfl_xor(lsum, 32);
    if (lane < 16) atomicAdd(&rowsum[lane], lsum);
    __syncthreads();
    if (tid < 16) rowinv[tid] = 1.f / rowsum[tid];
    __syncthreads();

    if (tid < 250) {
        const int c4 = tid * 4;
        const size_t obase = (size_t)(b * PP + p0) * NN;
#pragma unroll 4
        for (int r = 0; r < 16; r++) {
            v4h pv = *(const v4h*)&probs[r * 1028 + c4];
            float inv = rowinv[r];
            float4 ov;
            ov.x = (float)pv[0] * inv;
            ov.y = (float)pv[1] * inv;
            ov.z = (float)pv[2] * inv;
            ov.w = (float)pv[3] * inv;
            *(float4*)&out[obase + (size_t)r * NN + c4] = ov;
        }
    }
}

extern "C" void kernel_launch(void* const* d_in, const int* in_sizes, int n_in,
                              void* d_out, int out_size, void* d_ws, size_t ws_size,
                              hipStream_t stream) {
    const float* nodes = (const float*)d_in[0];
    const float* ln    = (const float*)d_in[1];
    const float* attr  = (const float*)d_in[2];
    const float* mask  = (const float*)d_in[3];
    const float* Wq    = (const float*)d_in[4];
    const float* Wk    = (const float*)d_in[5];
    const float* Wv    = (const float*)d_in[6];
    const float* Wo    = (const float*)d_in[7];
    const float* bo    = (const float*)d_in[8];
    float* out = (float*)d_out;

    // workspace layout (floats): Aout fp32 [16384*128], then fp16 Qh, Mh
    float*  Aout = (float*)d_ws;                       // 2,097,152 floats
    __fp16* Qh   = (__fp16*)(Aout + 2097152);          // 2,097,152 halfs
    __fp16* Mhh  = Qh + 2097152;                       // 2,097,152 halfs

    // d_out doubles as fp16 K/V scratch (fully rewritten every launch)
    __fp16* Kf = (__fp16*)d_out;
    __fp16* Vt = Kf + (size_t)BB * HH * NP * 16;

    hipLaunchKernelGGL(k1_qproj, dim3(256), dim3(256), 0, stream, ln, attr, Wq, Qh);
    hipLaunchKernelGGL(k2_kv, dim3(16, 64, 2), dim3(256), 0, stream, nodes, Wk, Wv, Kf, Vt);
    hipLaunchKernelGGL(k3_attn, dim3(1024), dim3(256), 0, stream, Qh, Kf, Vt, mask, Aout);
    hipLaunchKernelGGL(k4_mh, dim3(256), dim3(256), 0, stream, Aout, Wo, bo, Mhh);
    hipLaunchKernelGGL(k5_final, dim3(1024), dim3(256), 0, stream, nodes, Mhh, mask, out);
}

// Round 6
// 300.923 us; speedup vs baseline: 1.2060x; 1.0040x over previous
//
#include <hip/hip_runtime.h>

#define BB 64
#define PP 256
#define NN 1000
#define NP 1024   // padded KV rows (power of 2, zero-filled beyond NN)
#define EE 128
#define HH 8
#define DD 16
// H*D = 128

typedef __fp16 v4h __attribute__((ext_vector_type(4)));
typedef float v4f __attribute__((ext_vector_type(4)));

// Shared MFMA GEMM convention (validated in k3/k5 since R2):
//   af = X[m = lane&15][k = 4*(lane>>4)+j]      (v4h)
//   bf = W^T[n = lane&15][k = 4*(lane>>4)+j]    (v4h, from LDS)
//   D  = mfma(af, bf, acc):  acc[r] = C[m = 4*(lane>>4)+r][n = lane&15]

// ---------------------------------------------------------------------------
// k1: Q projection, MFMA.  Qh = 0.25 * (concat(ln, attr) @ Wq), fp16 out.
// attr (K-row 128) applied as rank-1 epilogue update.
// ---------------------------------------------------------------------------
__global__ __launch_bounds__(256) void k1_qproj(const float* __restrict__ ln,
                                                const float* __restrict__ attr,
                                                const float* __restrict__ Wq,
                                                __fp16* __restrict__ Qh) {
    __shared__ __fp16 wt[128 * 132];   // Wq^T[n][k], first 128 k-rows
    __shared__ float attrs[64];
    const int tid = threadIdx.x;
    const int row0 = blockIdx.x * 64;   // 256 blocks
    for (int i = tid; i < 128 * 128; i += 256) {
        int k = i >> 7, n = i & 127;
        wt[n * 132 + k] = (__fp16)Wq[i];
    }
    if (tid < 64) attrs[tid] = attr[row0 + tid];
    __syncthreads();

    const int wid = tid >> 6, lane = tid & 63;
    const int lp = lane & 15, lg = lane >> 4;
    const int rb = row0 + wid * 16;

    const float* arow = ln + (size_t)(rb + lp) * 128;
    v4f acc[8];
#pragma unroll
    for (int cf = 0; cf < 8; cf++) acc[cf] = (v4f){0.f, 0.f, 0.f, 0.f};

#pragma unroll
    for (int k0 = 0; k0 < 8; k0++) {
        float4 av = *(const float4*)&arow[k0 * 16 + 4 * lg];
        v4h af;
        af[0] = (__fp16)av.x; af[1] = (__fp16)av.y;
        af[2] = (__fp16)av.z; af[3] = (__fp16)av.w;
#pragma unroll
        for (int cf = 0; cf < 8; cf++) {
            v4h bf = *(const v4h*)&wt[(cf * 16 + lp) * 132 + k0 * 16 + 4 * lg];
            acc[cf] = __builtin_amdgcn_mfma_f32_16x16x16f16(af, bf, acc[cf], 0, 0, 0);
        }
    }

#pragma unroll
    for (int cf = 0; cf < 8; cf++) {
        const int col = cf * 16 + lp;
        const float w128 = Wq[128 * 128 + col];
#pragma unroll
        for (int r = 0; r < 4; r++) {
            const int rl = wid * 16 + 4 * lg + r;
            float v = (acc[cf][r] + attrs[rl] * w128) * 0.25f;
            Qh[(size_t)(row0 + rl) * 128 + col] = (__fp16)v;
        }
    }
}

// ---------------------------------------------------------------------------
// k2: K/V projection, MFMA.  blockIdx.z: 0 -> Kf [B,H,NP,16], 1 -> Vt tiled.
// Vt layout: [b,h, tile=n>>4, d, n&15] — each 16x16 V^T tile is 512 B dense.
// Rows padded to NP=1024, zero-filled beyond NN.
// ---------------------------------------------------------------------------
__global__ __launch_bounds__(256) void k2_kv(const float* __restrict__ nodes,
                                             const float* __restrict__ Wk,
                                             const float* __restrict__ Wv,
                                             __fp16* __restrict__ Kf,
                                             __fp16* __restrict__ Vt) {
    __shared__ __fp16 wt[128 * 132];   // W^T[n][k]
    const int tid = threadIdx.x;
    const int b = blockIdx.y;
    const int kv = blockIdx.z;
    const float* W = (kv == 0) ? Wk : Wv;
    for (int i = tid; i < 128 * 128; i += 256) {
        int k = i >> 7, n = i & 127;
        wt[n * 132 + k] = (__fp16)W[i];
    }
    __syncthreads();

    const int wid = tid >> 6, lane = tid & 63;
    const int lp = lane & 15, lg = lane >> 4;
    const int nb = blockIdx.x * 64 + wid * 16;   // 16 x-blocks -> rows 0..1023

    int nr = nb + lp;
    if (nr >= NN) nr = NN - 1;                   // clamp; garbage zeroed on store
    const float* arow = nodes + (size_t)(b * NN + nr) * 128;

    v4f acc[8];
#pragma unroll
    for (int cf = 0; cf < 8; cf++) acc[cf] = (v4f){0.f, 0.f, 0.f, 0.f};

#pragma unroll
    for (int k0 = 0; k0 < 8; k0++) {
        float4 av = *(const float4*)&arow[k0 * 16 + 4 * lg];
        v4h af;
        af[0] = (__fp16)av.x; af[1] = (__fp16)av.y;
        af[2] = (__fp16)av.z; af[3] = (__fp16)av.w;
#pragma unroll
        for (int cf = 0; cf < 8; cf++) {
            v4h bf = *(const v4h*)&wt[(cf * 16 + lp) * 132 + k0 * 16 + 4 * lg];
            acc[cf] = __builtin_amdgcn_mfma_f32_16x16x16f16(af, bf, acc[cf], 0, 0, 0);
        }
    }

    if (kv == 0) {
        // col = h*16 + d: cf = h, lp = d.  Kf[b,h,n,d], n = nb + 4*lg + r
#pragma unroll
        for (int cf = 0; cf < 8; cf++) {
            const size_t base = ((size_t)(b * HH + cf) << 14) + lp;
#pragma unroll
            for (int r = 0; r < 4; r++) {
                const int n = nb + 4 * lg + r;
                Kf[base + (size_t)n * 16] = (n < NN) ? (__fp16)acc[cf][r] : (__fp16)0.f;
            }
        }
    } else {
        // Vt[b,h,tile][d=lp][n&15 = 4*lg+r] (4 consecutive -> v4h)
#pragma unroll
        for (int cf = 0; cf < 8; cf++) {
            v4h pk;
#pragma unroll
            for (int r = 0; r < 4; r++) {
                const int n = nb + 4 * lg + r;
                pk[r] = (n < NN) ? (__fp16)acc[cf][r] : (__fp16)0.f;
            }
            *(v4h*)&Vt[((size_t)(b * HH + cf) << 14) + (size_t)(nb >> 4) * 256 +
                       lp * 16 + 4 * lg] = pk;
        }
    }
}

// ---------------------------------------------------------------------------
// k3: MFMA attention.  R9 structure (LDS-staged K/V double-buffer, 2 head-
// chains/wave, grid 1024).  Unchanged from R9.
// ---------------------------------------------------------------------------
__global__ __launch_bounds__(256) void k3_attn(const __fp16* __restrict__ Qh,
                                               const __fp16* __restrict__ Kf,
                                               const __fp16* __restrict__ Vt,
                                               const float* __restrict__ mask,
                                               float* __restrict__ Aout) {
    __shared__ __fp16 sh[2][4][256];   // [buf][chunk: Kh0,Kh1,Vh0,Vh1][16x16 tile]
    const int tid = threadIdx.x;
    const int bid = blockIdx.x;            // 1024
    const int b = bid & 63;                // bid&7 = b&7 -> XCD locality on b
    const int rest = bid >> 6;             // 0..15
    const int hg = rest & 3, pt = rest >> 2;
    const int h0 = hg * 2;
    const int p0 = pt * 64;

    const int wid = tid >> 6, lane = tid & 63;
    const int lp = lane & 15, lg = lane >> 4;
    const int pw = p0 + wid * 16;

    // staging source: wave w handles chunk w
    const __fp16* gsrc = ((wid < 2) ? Kf + ((size_t)(b * HH + h0 + wid) << 14)
                                    : Vt + ((size_t)(b * HH + h0 + wid - 2) << 14)) +
                         lane * 4;
    __fp16* sdst0 = &sh[0][wid][lane * 4];
    __fp16* sdst1 = &sh[1][wid][lane * 4];

    v4h qf[2];
    {
        const __fp16* qrow = Qh + (size_t)(b * PP + pw + lp) * 128 + h0 * 16 + 4 * lg;
        qf[0] = *(const v4h*)&qrow[0];
        qf[1] = *(const v4h*)&qrow[16];
    }

    const float* mrow = mask + (size_t)(b * PP + pw + lp) * NN;

    v4f acc[2];
    float lsum[2];
    acc[0] = (v4f){0.f, 0.f, 0.f, 0.f};
    acc[1] = (v4f){0.f, 0.f, 0.f, 0.f};
    lsum[0] = 0.f; lsum[1] = 0.f;
    const v4f zero4 = {0.f, 0.f, 0.f, 0.f};

    // prologue: stage tile 0 into buf0; preload tile-1 regs and mask(0)
    v4h st[2];
    float4 mv[2];
    st[0] = *(const v4h*)(gsrc);            // tile 0
    *(v4h*)sdst0 = st[0];
    st[1] = *(const v4h*)(gsrc + 256);      // tile 1 (written to buf1 in iter 0)
    mv[0] = *(const float4*)&mrow[4 * lg];  // mask step 0
    __syncthreads();

    // invariants at top of iter s: sh[s&1] holds tile s; st[(s+1)&1] holds
    // tile s+1; mv[s&1] holds mask(s).
#pragma unroll 2
    for (int s = 0; s < 62; s++) {
        const int p = s & 1;
        // prefetch: tile s+2 regs, mask s+1
        if (s + 2 <= 62) st[p] = *(const v4h*)(gsrc + (s + 2) * 256);
        {
            int moff = (s + 1) * 16 + 4 * lg;
            if (moff > 996) moff = 996;     // only clamps at s+1 == 62
            mv[p ^ 1] = *(const float4*)&mrow[moff];
        }

        // compute step s from sh[p]
        v4h kf0 = *(const v4h*)&sh[p][0][lp * 16 + 4 * lg];
        v4h kf1 = *(const v4h*)&sh[p][1][lp * 16 + 4 * lg];
        v4h vf0 = *(const v4h*)&sh[p][2][lp * 16 + 4 * lg];
        v4h vf1 = *(const v4h*)&sh[p][3][lp * 16 + 4 * lg];
        const float4 m = mv[p];
        {
            v4f sc = __builtin_amdgcn_mfma_f32_16x16x16f16(kf0, qf[0], zero4, 0, 0, 0);
            float w0 = __expf(sc[0] + m.x);
            float w1 = __expf(sc[1] + m.y);
            float w2 = __expf(sc[2] + m.z);
            float w3 = __expf(sc[3] + m.w);
            lsum[0] += (w0 + w1) + (w2 + w3);
            v4h wf;
            wf[0] = (__fp16)w0; wf[1] = (__fp16)w1; wf[2] = (__fp16)w2; wf[3] = (__fp16)w3;
            acc[0] = __builtin_amdgcn_mfma_f32_16x16x16f16(wf, vf0, acc[0], 0, 0, 0);
        }
        {
            v4f sc = __builtin_amdgcn_mfma_f32_16x16x16f16(kf1, qf[1], zero4, 0, 0, 0);
            float w0 = __expf(sc[0] + m.x);
            float w1 = __expf(sc[1] + m.y);
            float w2 = __expf(sc[2] + m.z);
            float w3 = __expf(sc[3] + m.w);
            lsum[1] += (w0 + w1) + (w2 + w3);
            v4h wf;
            wf[0] = (__fp16)w0; wf[1] = (__fp16)w1; wf[2] = (__fp16)w2; wf[3] = (__fp16)w3;
            acc[1] = __builtin_amdgcn_mfma_f32_16x16x16f16(wf, vf1, acc[1], 0, 0, 0);
        }

        // publish tile s+1 into the other buffer (safe: all waves finished
        // reading it in iter s-1 before the barrier below)
        *(v4h*)((p == 0) ? sdst1 : sdst0) = st[p ^ 1];
        __syncthreads();
    }

    {   // tail step s=62 (parity 0): n = 992 + 4*lg + r, bounds-guarded
        const int nl = 992;
        const float4 m = mv[0];
        const bool c0 = (nl + 4 * lg + 0 < NN), c1 = (nl + 4 * lg + 1 < NN);
        const bool c2 = (nl + 4 * lg + 2 < NN), c3 = (nl + 4 * lg + 3 < NN);
        v4h kf0 = *(const v4h*)&sh[0][0][lp * 16 + 4 * lg];
        v4h kf1 = *(const v4h*)&sh[0][1][lp * 16 + 4 * lg];
        v4h vf0 = *(const v4h*)&sh[0][2][lp * 16 + 4 * lg];
        v4h vf1 = *(const v4h*)&sh[0][3][lp * 16 + 4 * lg];
        {
            v4f sc = __builtin_amdgcn_mfma_f32_16x16x16f16(kf0, qf[0], zero4, 0, 0, 0);
            float w0 = c0 ? __expf(sc[0] + m.x) : 0.f;
            float w1 = c1 ? __expf(sc[1] + m.y) : 0.f;
            float w2 = c2 ? __expf(sc[2] + m.z) : 0.f;
            float w3 = c3 ? __expf(sc[3] + m.w) : 0.f;
            lsum[0] += (w0 + w1) + (w2 + w3);
            v4h wf;
            wf[0] = (__fp16)w0; wf[1] = (__fp16)w1; wf[2] = (__fp16)w2; wf[3] = (__fp16)w3;
            acc[0] = __builtin_amdgcn_mfma_f32_16x16x16f16(wf, vf0, acc[0], 0, 0, 0);
        }
        {
            v4f sc = __builtin_amdgcn_mfma_f32_16x16x16f16(kf1, qf[1], zero4, 0, 0, 0);
            float w0 = c0 ? __expf(sc[0] + m.x) : 0.f;
            float w1 = c1 ? __expf(sc[1] + m.y) : 0.f;
            float w2 = c2 ? __expf(sc[2] + m.z) : 0.f;
            float w3 = c3 ? __expf(sc[3] + m.w) : 0.f;
            lsum[1] += (w0 + w1) + (w2 + w3);
            v4h wf;
            wf[0] = (__fp16)w0; wf[1] = (__fp16)w1; wf[2] = (__fp16)w2; wf[3] = (__fp16)w3;
            acc[1] = __builtin_amdgcn_mfma_f32_16x16x16f16(wf, vf1, acc[1], 0, 0, 0);
        }
    }

#pragma unroll
    for (int j = 0; j < 2; j++) {
        float l = lsum[j];
        l += __shfl_xor(l, 16);
        l += __shfl_xor(l, 32);
#pragma unroll
        for (int r = 0; r < 4; r++) {
            float denom = __shfl(l, 4 * lg + r);
            float inv = 1.f / denom;
            Aout[(size_t)(b * PP + pw + 4 * lg + r) * 128 + (h0 + j) * 16 + lp] =
                acc[j][r] * inv;
        }
    }
}

// ---------------------------------------------------------------------------
// k4: mh MFMA.  Mh_h = fp16( (Aout @ Wo + bo) * (1/sqrt(128)) )
// ---------------------------------------------------------------------------
__global__ __launch_bounds__(256) void k4_mh(const float* __restrict__ Ain,
                                             const float* __restrict__ Wo,
                                             const float* __restrict__ bo,
                                             __fp16* __restrict__ Mh) {
    __shared__ __fp16 wt[128 * 132];   // Wo^T[n][k]
    const int tid = threadIdx.x;
    const int row0 = blockIdx.x * 64;
    for (int i = tid; i < 128 * 128; i += 256) {
        int k = i >> 7, n = i & 127;
        wt[n * 132 + k] = (__fp16)Wo[i];
    }
    __syncthreads();

    const int wid = tid >> 6, lane = tid & 63;
    const int lp = lane & 15, lg = lane >> 4;
    const int rb = row0 + wid * 16;

    const float* arow = Ain + (size_t)(rb + lp) * 128;
    v4f acc[8];
#pragma unroll
    for (int cf = 0; cf < 8; cf++) acc[cf] = (v4f){0.f, 0.f, 0.f, 0.f};

#pragma unroll
    for (int k0 = 0; k0 < 8; k0++) {
        float4 av = *(const float4*)&arow[k0 * 16 + 4 * lg];
        v4h af;
        af[0] = (__fp16)av.x; af[1] = (__fp16)av.y;
        af[2] = (__fp16)av.z; af[3] = (__fp16)av.w;
#pragma unroll
        for (int cf = 0; cf < 8; cf++) {
            v4h bf = *(const v4h*)&wt[(cf * 16 + lp) * 132 + k0 * 16 + 4 * lg];
            acc[cf] = __builtin_amdgcn_mfma_f32_16x16x16f16(af, bf, acc[cf], 0, 0, 0);
        }
    }

    const float scale = 0.08838834764831845f;   // 1/sqrt(128)
#pragma unroll
    for (int cf = 0; cf < 8; cf++) {
        const int col = cf * 16 + lp;
        const float bb = bo[col];
#pragma unroll
        for (int r = 0; r < 4; r++) {
            const int rl = wid * 16 + 4 * lg + r;
            Mh[(size_t)(row0 + rl) * 128 + col] = (__fp16)((acc[cf][r] + bb) * scale);
        }
    }
}

// ---------------------------------------------------------------------------
// k5: final scoring + tanh-clip softmax.
// R10: register double-buffered prefetch of nodes (8 float4) + mask (float4)
// one step ahead -> doubles in-flight read bytes (Little's-law fix).
// Numerics identical to R9 (same loads, same fp16 roundings, same order).
// ---------------------------------------------------------------------------
__device__ __forceinline__ void k5_prefetch(int s, int wid, int lp, int lg,
                                            const float* __restrict__ nbase,
                                            const float* __restrict__ mkrow,
                                            float4 (&nb)[8], float4& mv) {
    int nr = s * 64 + wid * 16 + lp;
    if (nr >= NN) nr = NN - 1;
    const float* a = nbase + (size_t)nr * 128 + 4 * lg;
#pragma unroll
    for (int ec = 0; ec < 8; ec++) nb[ec] = *(const float4*)&a[ec * 16];
    int mc = s * 64 + wid * 16 + 4 * lg;
    if (mc > 996) mc = 996;            // clamp only affects lanes whose cols are OOB
    mv = *(const float4*)&mkrow[mc];
}

__device__ __forceinline__ void k5_compute(int s, int wid, int lp, int lg,
                                           const v4h (&bf)[8], const float4 (&nb)[8],
                                           const float4 mv, float& lsum,
                                           __fp16* __restrict__ probs) {
    const v4f zero4 = {0.f, 0.f, 0.f, 0.f};
    v4f acc = zero4;
#pragma unroll
    for (int ec = 0; ec < 8; ec++) {
        float4 av = nb[ec];
        v4h af;
        af[0] = (__fp16)av.x; af[1] = (__fp16)av.y;
        af[2] = (__fp16)av.z; af[3] = (__fp16)av.w;
        acc = __builtin_amdgcn_mfma_f32_16x16x16f16(af, bf[ec], acc, 0, 0, 0);
    }
    const int nt = s * 64 + wid * 16;
    const int nb4 = nt + 4 * lg;
    v4h wf;
    if (nt + 15 < NN) {
        float e0 = __expf(2.f * acc[0]);
        float e1 = __expf(2.f * acc[1]);
        float e2 = __expf(2.f * acc[2]);
        float e3 = __expf(2.f * acc[3]);
        float w0 = __expf(fmaf(-20.f, __builtin_amdgcn_rcpf(e0 + 1.f), mv.x));
        float w1 = __expf(fmaf(-20.f, __builtin_amdgcn_rcpf(e1 + 1.f), mv.y));
        float w2 = __expf(fmaf(-20.f, __builtin_amdgcn_rcpf(e2 + 1.f), mv.z));
        float w3 = __expf(fmaf(-20.f, __builtin_amdgcn_rcpf(e3 + 1.f), mv.w));
        lsum += (w0 + w1) + (w2 + w3);
        wf[0] = (__fp16)w0; wf[1] = (__fp16)w1; wf[2] = (__fp16)w2; wf[3] = (__fp16)w3;
    } else {
        float w0 = 0.f, w1 = 0.f, w2 = 0.f, w3 = 0.f;
        if (nb4 + 0 < NN) {
            float e = __expf(2.f * acc[0]);
            w0 = __expf(fmaf(-20.f, __builtin_amdgcn_rcpf(e + 1.f), mv.x));
        }
        if (nb4 + 1 < NN) {
            float e = __expf(2.f * acc[1]);
            w1 = __expf(fmaf(-20.f, __builtin_amdgcn_rcpf(e + 1.f), mv.y));
        }
        if (nb4 + 2 < NN) {
            float e = __expf(2.f * acc[2]);
            w2 = __expf(fmaf(-20.f, __builtin_amdgcn_rcpf(e + 1.f), mv.z));
        }
        if (nb4 + 3 < NN) {
            float e = __expf(2.f * acc[3]);
            w3 = __expf(fmaf(-20.f, __builtin_amdgcn_rcpf(e + 1.f), mv.w));
        }
        lsum += (w0 + w1) + (w2 + w3);
        wf[0] = (__fp16)w0; wf[1] = (__fp16)w1; wf[2] = (__fp16)w2; wf[3] = (__fp16)w3;
    }
    *(v4h*)&probs[lp * 1028 + nb4] = wf;
}

__global__ __launch_bounds__(256, 4) void k5_final(const float* __restrict__ nodes,
                                                   const __fp16* __restrict__ Mh,
                                                   const float* __restrict__ mask,
                                                   float* __restrict__ out) {
    __shared__ __fp16 probs[16 * 1028];
    __shared__ float rowsum[16];
    __shared__ float rowinv[16];
    const int tid = threadIdx.x;
    const int bid = blockIdx.x;          // 1024 = 64 b x 16 pt, XCD-swizzled
    const int xcd = bid & 7;
    const int rest = bid >> 3;
    const int pt = rest & 15;
    const int b = ((rest >> 4) << 3) + xcd;
    const int p0 = pt * 16;

    if (tid < 16) rowsum[tid] = 0.f;

    const int wid = tid >> 6, lane = tid & 63;
    const int lp = lane & 15, lg = lane >> 4;

    v4h bf[8];
    {
        const __fp16* mhrow = Mh + (size_t)(b * PP + p0 + lp) * 128;
#pragma unroll
        for (int ec = 0; ec < 8; ec++)
            bf[ec] = *(const v4h*)&mhrow[ec * 16 + 4 * lg];
    }
    __syncthreads();

    float lsum = 0.f;
    const float* nbase = nodes + (size_t)b * NN * 128;
    const float* mkrow = mask + (size_t)(b * PP + p0 + lp) * NN;

    // ping-pong register buffers; prefetch step s+1 while computing step s
    float4 nbA[8], nbB[8];
    float4 mvA, mvB;
    k5_prefetch(0, wid, lp, lg, nbase, mkrow, nbA, mvA);
    for (int s2 = 0; s2 < 8; s2++) {
        const int s = 2 * s2;
        k5_prefetch(s + 1, wid, lp, lg, nbase, mkrow, nbB, mvB);
        k5_compute(s, wid, lp, lg, bf, nbA, mvA, lsum, probs);
        if (s2 < 7) k5_prefetch(s + 2, wid, lp, lg, nbase, mkrow, nbA, mvA);
        k5_compute(s + 1, wid, lp, lg, bf, nbB, mvB, lsum, probs);
    }

    lsum += __shfl_xor(lsum, 16);
    lsum += __shfl_xor(lsum, 32);
    if (lane < 16) atomicAdd(&rowsum[lane], lsum);
    __syncthreads();
    if (tid < 16) rowinv[tid] = 1.f / rowsum[tid];
    __syncthreads();

    if (tid < 250) {
        const int c4 = tid * 4;
        const size_t obase = (size_t)(b * PP + p0) * NN;
#pragma unroll 4
        for (int r = 0; r < 16; r++) {
            v4h pv = *(const v4h*)&probs[r * 1028 + c4];
            float inv = rowinv[r];
            float4 ov;
            ov.x = (float)pv[0] * inv;
            ov.y = (float)pv[1] * inv;
            ov.z = (float)pv[2] * inv;
            ov.w = (float)pv[3] * inv;
            *(float4*)&out[obase + (size_t)r * NN + c4] = ov;
        }
    }
}

extern "C" void kernel_launch(void* const* d_in, const int* in_sizes, int n_in,
                              void* d_out, int out_size, void* d_ws, size_t ws_size,
                              hipStream_t stream) {
    const float* nodes = (const float*)d_in[0];
    const float* ln    = (const float*)d_in[1];
    const float* attr  = (const float*)d_in[2];
    const float* mask  = (const float*)d_in[3];
    const float* Wq    = (const float*)d_in[4];
    const float* Wk    = (const float*)d_in[5];
    const float* Wv    = (const float*)d_in[6];
    const float* Wo    = (const float*)d_in[7];
    const float* bo    = (const float*)d_in[8];
    float* out = (float*)d_out;

    // workspace layout (floats): Aout fp32 [16384*128], then fp16 Qh, Mh
    float*  Aout = (float*)d_ws;                       // 2,097,152 floats
    __fp16* Qh   = (__fp16*)(Aout + 2097152);          // 2,097,152 halfs
    __fp16* Mhh  = Qh + 2097152;                       // 2,097,152 halfs

    // d_out doubles as fp16 K/V scratch (fully rewritten every launch)
    __fp16* Kf = (__fp16*)d_out;
    __fp16* Vt = Kf + (size_t)BB * HH * NP * 16;

    hipLaunchKernelGGL(k1_qproj, dim3(256), dim3(256), 0, stream, ln, attr, Wq, Qh);
    hipLaunchKernelGGL(k2_kv, dim3(16, 64, 2), dim3(256), 0, stream, nodes, Wk, Wv, Kf, Vt);
    hipLaunchKernelGGL(k3_attn, dim3(1024), dim3(256), 0, stream, Qh, Kf, Vt, mask, Aout);
    hipLaunchKernelGGL(k4_mh, dim3(256), dim3(256), 0, stream, Aout, Wo, bo, Mhh);
    hipLaunchKernelGGL(k5_final, dim3(1024), dim3(256), 0, stream, nodes, Mhh, mask, out);
}

// Round 7
// 284.130 us; speedup vs baseline: 1.2772x; 1.0591x over previous
//
#include <hip/hip_runtime.h>

#define BB 64
#define PP 256
#define NN 1000
#define NP 1024   // padded KV rows (power of 2, zero-filled beyond NN)
#define EE 128
#define HH 8
#define DD 16
// H*D = 128

typedef __fp16 v4h __attribute__((ext_vector_type(4)));
typedef float v4f __attribute__((ext_vector_type(4)));

// Shared MFMA GEMM convention (validated in k3/k5 since R2):
//   af = X[m = lane&15][k = 4*(lane>>4)+j]      (v4h)
//   bf = W^T[n = lane&15][k = 4*(lane>>4)+j]    (v4h, from LDS)
//   D  = mfma(af, bf, acc):  acc[r] = C[m = 4*(lane>>4)+r][n = lane&15]

// ---------------------------------------------------------------------------
// k1: Q projection, MFMA.  Qh = 0.25 * (concat(ln, attr) @ Wq), fp16 out.
// ---------------------------------------------------------------------------
__global__ __launch_bounds__(256) void k1_qproj(const float* __restrict__ ln,
                                                const float* __restrict__ attr,
                                                const float* __restrict__ Wq,
                                                __fp16* __restrict__ Qh) {
    __shared__ __fp16 wt[128 * 132];   // Wq^T[n][k], first 128 k-rows
    __shared__ float attrs[64];
    const int tid = threadIdx.x;
    const int row0 = blockIdx.x * 64;   // 256 blocks
    for (int i = tid; i < 128 * 128; i += 256) {
        int k = i >> 7, n = i & 127;
        wt[n * 132 + k] = (__fp16)Wq[i];
    }
    if (tid < 64) attrs[tid] = attr[row0 + tid];
    __syncthreads();

    const int wid = tid >> 6, lane = tid & 63;
    const int lp = lane & 15, lg = lane >> 4;
    const int rb = row0 + wid * 16;

    const float* arow = ln + (size_t)(rb + lp) * 128;
    v4f acc[8];
#pragma unroll
    for (int cf = 0; cf < 8; cf++) acc[cf] = (v4f){0.f, 0.f, 0.f, 0.f};

#pragma unroll
    for (int k0 = 0; k0 < 8; k0++) {
        float4 av = *(const float4*)&arow[k0 * 16 + 4 * lg];
        v4h af;
        af[0] = (__fp16)av.x; af[1] = (__fp16)av.y;
        af[2] = (__fp16)av.z; af[3] = (__fp16)av.w;
#pragma unroll
        for (int cf = 0; cf < 8; cf++) {
            v4h bf = *(const v4h*)&wt[(cf * 16 + lp) * 132 + k0 * 16 + 4 * lg];
            acc[cf] = __builtin_amdgcn_mfma_f32_16x16x16f16(af, bf, acc[cf], 0, 0, 0);
        }
    }

#pragma unroll
    for (int cf = 0; cf < 8; cf++) {
        const int col = cf * 16 + lp;
        const float w128 = Wq[128 * 128 + col];
#pragma unroll
        for (int r = 0; r < 4; r++) {
            const int rl = wid * 16 + 4 * lg + r;
            float v = (acc[cf][r] + attrs[rl] * w128) * 0.25f;
            Qh[(size_t)(row0 + rl) * 128 + col] = (__fp16)v;
        }
    }
}

// ---------------------------------------------------------------------------
// k2: K/V projection, MFMA.  blockIdx.z: 0 -> Kf [B,H,NP,16], 1 -> Vt tiled.
// Vt layout: [b,h, tile=n>>4, d, n&15] — each 16x16 V^T tile is 512 B dense.
// ---------------------------------------------------------------------------
__global__ __launch_bounds__(256) void k2_kv(const float* __restrict__ nodes,
                                             const float* __restrict__ Wk,
                                             const float* __restrict__ Wv,
                                             __fp16* __restrict__ Kf,
                                             __fp16* __restrict__ Vt) {
    __shared__ __fp16 wt[128 * 132];   // W^T[n][k]
    const int tid = threadIdx.x;
    const int b = blockIdx.y;
    const int kv = blockIdx.z;
    const float* W = (kv == 0) ? Wk : Wv;
    for (int i = tid; i < 128 * 128; i += 256) {
        int k = i >> 7, n = i & 127;
        wt[n * 132 + k] = (__fp16)W[i];
    }
    __syncthreads();

    const int wid = tid >> 6, lane = tid & 63;
    const int lp = lane & 15, lg = lane >> 4;
    const int nb = blockIdx.x * 64 + wid * 16;   // 16 x-blocks -> rows 0..1023

    int nr = nb + lp;
    if (nr >= NN) nr = NN - 1;                   // clamp; garbage zeroed on store
    const float* arow = nodes + (size_t)(b * NN + nr) * 128;

    v4f acc[8];
#pragma unroll
    for (int cf = 0; cf < 8; cf++) acc[cf] = (v4f){0.f, 0.f, 0.f, 0.f};

#pragma unroll
    for (int k0 = 0; k0 < 8; k0++) {
        float4 av = *(const float4*)&arow[k0 * 16 + 4 * lg];
        v4h af;
        af[0] = (__fp16)av.x; af[1] = (__fp16)av.y;
        af[2] = (__fp16)av.z; af[3] = (__fp16)av.w;
#pragma unroll
        for (int cf = 0; cf < 8; cf++) {
            v4h bf = *(const v4h*)&wt[(cf * 16 + lp) * 132 + k0 * 16 + 4 * lg];
            acc[cf] = __builtin_amdgcn_mfma_f32_16x16x16f16(af, bf, acc[cf], 0, 0, 0);
        }
    }

    if (kv == 0) {
        // col = h*16 + d: cf = h, lp = d.  Kf[b,h,n,d], n = nb + 4*lg + r
#pragma unroll
        for (int cf = 0; cf < 8; cf++) {
            const size_t base = ((size_t)(b * HH + cf) << 14) + lp;
#pragma unroll
            for (int r = 0; r < 4; r++) {
                const int n = nb + 4 * lg + r;
                Kf[base + (size_t)n * 16] = (n < NN) ? (__fp16)acc[cf][r] : (__fp16)0.f;
            }
        }
    } else {
        // Vt[b,h,tile][d=lp][n&15 = 4*lg+r] (4 consecutive -> v4h)
#pragma unroll
        for (int cf = 0; cf < 8; cf++) {
            v4h pk;
#pragma unroll
            for (int r = 0; r < 4; r++) {
                const int n = nb + 4 * lg + r;
                pk[r] = (n < NN) ? (__fp16)acc[cf][r] : (__fp16)0.f;
            }
            *(v4h*)&Vt[((size_t)(b * HH + cf) << 14) + (size_t)(nb >> 4) * 256 +
                       lp * 16 + 4 * lg] = pk;
        }
    }
}

// ---------------------------------------------------------------------------
// k3: MFMA attention.  R9 structure (LDS-staged K/V double-buffer, 2 head-
// chains/wave, grid 1024).  R11: Aout now fp16 (identical numerics — fp16
// rounding moved from k4's load to k3's store); halves write traffic.
// ---------------------------------------------------------------------------
__global__ __launch_bounds__(256) void k3_attn(const __fp16* __restrict__ Qh,
                                               const __fp16* __restrict__ Kf,
                                               const __fp16* __restrict__ Vt,
                                               const float* __restrict__ mask,
                                               __fp16* __restrict__ Aout) {
    __shared__ __fp16 sh[2][4][256];   // [buf][chunk: Kh0,Kh1,Vh0,Vh1][16x16 tile]
    const int tid = threadIdx.x;
    const int bid = blockIdx.x;            // 1024
    const int b = bid & 63;                // bid&7 = b&7 -> XCD locality on b
    const int rest = bid >> 6;             // 0..15
    const int hg = rest & 3, pt = rest >> 2;
    const int h0 = hg * 2;
    const int p0 = pt * 64;

    const int wid = tid >> 6, lane = tid & 63;
    const int lp = lane & 15, lg = lane >> 4;
    const int pw = p0 + wid * 16;

    // staging source: wave w handles chunk w
    const __fp16* gsrc = ((wid < 2) ? Kf + ((size_t)(b * HH + h0 + wid) << 14)
                                    : Vt + ((size_t)(b * HH + h0 + wid - 2) << 14)) +
                         lane * 4;
    __fp16* sdst0 = &sh[0][wid][lane * 4];
    __fp16* sdst1 = &sh[1][wid][lane * 4];

    v4h qf[2];
    {
        const __fp16* qrow = Qh + (size_t)(b * PP + pw + lp) * 128 + h0 * 16 + 4 * lg;
        qf[0] = *(const v4h*)&qrow[0];
        qf[1] = *(const v4h*)&qrow[16];
    }

    const float* mrow = mask + (size_t)(b * PP + pw + lp) * NN;

    v4f acc[2];
    float lsum[2];
    acc[0] = (v4f){0.f, 0.f, 0.f, 0.f};
    acc[1] = (v4f){0.f, 0.f, 0.f, 0.f};
    lsum[0] = 0.f; lsum[1] = 0.f;
    const v4f zero4 = {0.f, 0.f, 0.f, 0.f};

    // prologue: stage tile 0 into buf0; preload tile-1 regs and mask(0)
    v4h st[2];
    float4 mv[2];
    st[0] = *(const v4h*)(gsrc);            // tile 0
    *(v4h*)sdst0 = st[0];
    st[1] = *(const v4h*)(gsrc + 256);      // tile 1 (written to buf1 in iter 0)
    mv[0] = *(const float4*)&mrow[4 * lg];  // mask step 0
    __syncthreads();

    // invariants at top of iter s: sh[s&1] holds tile s; st[(s+1)&1] holds
    // tile s+1; mv[s&1] holds mask(s).
#pragma unroll 2
    for (int s = 0; s < 62; s++) {
        const int p = s & 1;
        // prefetch: tile s+2 regs, mask s+1
        if (s + 2 <= 62) st[p] = *(const v4h*)(gsrc + (s + 2) * 256);
        {
            int moff = (s + 1) * 16 + 4 * lg;
            if (moff > 996) moff = 996;     // only clamps at s+1 == 62
            mv[p ^ 1] = *(const float4*)&mrow[moff];
        }

        // compute step s from sh[p]
        v4h kf0 = *(const v4h*)&sh[p][0][lp * 16 + 4 * lg];
        v4h kf1 = *(const v4h*)&sh[p][1][lp * 16 + 4 * lg];
        v4h vf0 = *(const v4h*)&sh[p][2][lp * 16 + 4 * lg];
        v4h vf1 = *(const v4h*)&sh[p][3][lp * 16 + 4 * lg];
        const float4 m = mv[p];
        {
            v4f sc = __builtin_amdgcn_mfma_f32_16x16x16f16(kf0, qf[0], zero4, 0, 0, 0);
            float w0 = __expf(sc[0] + m.x);
            float w1 = __expf(sc[1] + m.y);
            float w2 = __expf(sc[2] + m.z);
            float w3 = __expf(sc[3] + m.w);
            lsum[0] += (w0 + w1) + (w2 + w3);
            v4h wf;
            wf[0] = (__fp16)w0; wf[1] = (__fp16)w1; wf[2] = (__fp16)w2; wf[3] = (__fp16)w3;
            acc[0] = __builtin_amdgcn_mfma_f32_16x16x16f16(wf, vf0, acc[0], 0, 0, 0);
        }
        {
            v4f sc = __builtin_amdgcn_mfma_f32_16x16x16f16(kf1, qf[1], zero4, 0, 0, 0);
            float w0 = __expf(sc[0] + m.x);
            float w1 = __expf(sc[1] + m.y);
            float w2 = __expf(sc[2] + m.z);
            float w3 = __expf(sc[3] + m.w);
            lsum[1] += (w0 + w1) + (w2 + w3);
            v4h wf;
            wf[0] = (__fp16)w0; wf[1] = (__fp16)w1; wf[2] = (__fp16)w2; wf[3] = (__fp16)w3;
            acc[1] = __builtin_amdgcn_mfma_f32_16x16x16f16(wf, vf1, acc[1], 0, 0, 0);
        }

        // publish tile s+1 into the other buffer (safe: all waves finished
        // reading it in iter s-1 before the barrier below)
        *(v4h*)((p == 0) ? sdst1 : sdst0) = st[p ^ 1];
        __syncthreads();
    }

    {   // tail step s=62 (parity 0): n = 992 + 4*lg + r, bounds-guarded
        const int nl = 992;
        const float4 m = mv[0];
        const bool c0 = (nl + 4 * lg + 0 < NN), c1 = (nl + 4 * lg + 1 < NN);
        const bool c2 = (nl + 4 * lg + 2 < NN), c3 = (nl + 4 * lg + 3 < NN);
        v4h kf0 = *(const v4h*)&sh[0][0][lp * 16 + 4 * lg];
        v4h kf1 = *(const v4h*)&sh[0][1][lp * 16 + 4 * lg];
        v4h vf0 = *(const v4h*)&sh[0][2][lp * 16 + 4 * lg];
        v4h vf1 = *(const v4h*)&sh[0][3][lp * 16 + 4 * lg];
        {
            v4f sc = __builtin_amdgcn_mfma_f32_16x16x16f16(kf0, qf[0], zero4, 0, 0, 0);
            float w0 = c0 ? __expf(sc[0] + m.x) : 0.f;
            float w1 = c1 ? __expf(sc[1] + m.y) : 0.f;
            float w2 = c2 ? __expf(sc[2] + m.z) : 0.f;
            float w3 = c3 ? __expf(sc[3] + m.w) : 0.f;
            lsum[0] += (w0 + w1) + (w2 + w3);
            v4h wf;
            wf[0] = (__fp16)w0; wf[1] = (__fp16)w1; wf[2] = (__fp16)w2; wf[3] = (__fp16)w3;
            acc[0] = __builtin_amdgcn_mfma_f32_16x16x16f16(wf, vf0, acc[0], 0, 0, 0);
        }
        {
            v4f sc = __builtin_amdgcn_mfma_f32_16x16x16f16(kf1, qf[1], zero4, 0, 0, 0);
            float w0 = c0 ? __expf(sc[0] + m.x) : 0.f;
            float w1 = c1 ? __expf(sc[1] + m.y) : 0.f;
            float w2 = c2 ? __expf(sc[2] + m.z) : 0.f;
            float w3 = c3 ? __expf(sc[3] + m.w) : 0.f;
            lsum[1] += (w0 + w1) + (w2 + w3);
            v4h wf;
            wf[0] = (__fp16)w0; wf[1] = (__fp16)w1; wf[2] = (__fp16)w2; wf[3] = (__fp16)w3;
            acc[1] = __builtin_amdgcn_mfma_f32_16x16x16f16(wf, vf1, acc[1], 0, 0, 0);
        }
    }

#pragma unroll
    for (int j = 0; j < 2; j++) {
        float l = lsum[j];
        l += __shfl_xor(l, 16);
        l += __shfl_xor(l, 32);
#pragma unroll
        for (int r = 0; r < 4; r++) {
            float denom = __shfl(l, 4 * lg + r);
            float inv = 1.f / denom;
            Aout[(size_t)(b * PP + pw + 4 * lg + r) * 128 + (h0 + j) * 16 + lp] =
                (__fp16)(acc[j][r] * inv);
        }
    }
}

// ---------------------------------------------------------------------------
// k4: mh MFMA.  Ain now fp16 (values identical to before — see k3 note).
// ---------------------------------------------------------------------------
__global__ __launch_bounds__(256) void k4_mh(const __fp16* __restrict__ Ain,
                                             const float* __restrict__ Wo,
                                             const float* __restrict__ bo,
                                             __fp16* __restrict__ Mh) {
    __shared__ __fp16 wt[128 * 132];   // Wo^T[n][k]
    const int tid = threadIdx.x;
    const int row0 = blockIdx.x * 64;
    for (int i = tid; i < 128 * 128; i += 256) {
        int k = i >> 7, n = i & 127;
        wt[n * 132 + k] = (__fp16)Wo[i];
    }
    __syncthreads();

    const int wid = tid >> 6, lane = tid & 63;
    const int lp = lane & 15, lg = lane >> 4;
    const int rb = row0 + wid * 16;

    const __fp16* arow = Ain + (size_t)(rb + lp) * 128;
    v4f acc[8];
#pragma unroll
    for (int cf = 0; cf < 8; cf++) acc[cf] = (v4f){0.f, 0.f, 0.f, 0.f};

#pragma unroll
    for (int k0 = 0; k0 < 8; k0++) {
        v4h af = *(const v4h*)&arow[k0 * 16 + 4 * lg];
#pragma unroll
        for (int cf = 0; cf < 8; cf++) {
            v4h bf = *(const v4h*)&wt[(cf * 16 + lp) * 132 + k0 * 16 + 4 * lg];
            acc[cf] = __builtin_amdgcn_mfma_f32_16x16x16f16(af, bf, acc[cf], 0, 0, 0);
        }
    }

    const float scale = 0.08838834764831845f;   // 1/sqrt(128)
#pragma unroll
    for (int cf = 0; cf < 8; cf++) {
        const int col = cf * 16 + lp;
        const float bb = bo[col];
#pragma unroll
        for (int r = 0; r < 4; r++) {
            const int rl = wid * 16 + 4 * lg + r;
            Mh[(size_t)(row0 + rl) * 128 + col] = (__fp16)((acc[cf][r] + bb) * scale);
        }
    }
}

// ---------------------------------------------------------------------------
// k5: final scoring + tanh-clip softmax.
// R11: 512-thread blocks, 32 p-rows/block (2 bf-subtiles share each nodes
// fragment -> nodes L1/L2 traffic halves), 8 node-steps of 128 rows,
// fp32 nodes register double-buffer, 2 independent MFMA chains per step.
// ---------------------------------------------------------------------------
__device__ __forceinline__ void k5_pref(int s, int wid, int lp, int lg,
                                        const float* __restrict__ nbase,
                                        float4 (&nb)[8]) {
    int nr = s * 128 + wid * 16 + lp;
    if (nr >= NN) nr = NN - 1;
    const float* a = nbase + (size_t)nr * 128 + 4 * lg;
#pragma unroll
    for (int ec = 0; ec < 8; ec++) nb[ec] = *(const float4*)&a[ec * 16];
}

__device__ __forceinline__ void k5_comp(int s, int wid, int lp, int lg,
                                        const v4h (&bf0)[8], const v4h (&bf1)[8],
                                        const float4 (&nb)[8],
                                        const float* __restrict__ mk0,
                                        const float* __restrict__ mk1,
                                        float& ls0, float& ls1,
                                        __fp16* __restrict__ probs) {
    const v4f zero4 = {0.f, 0.f, 0.f, 0.f};
    int mc = s * 128 + wid * 16 + 4 * lg;
    if (mc > 996) mc = 996;
    float4 m0 = *(const float4*)&mk0[mc];
    float4 m1 = *(const float4*)&mk1[mc];
    v4f a0 = zero4, a1 = zero4;
#pragma unroll
    for (int ec = 0; ec < 8; ec++) {
        float4 av = nb[ec];
        v4h af;
        af[0] = (__fp16)av.x; af[1] = (__fp16)av.y;
        af[2] = (__fp16)av.z; af[3] = (__fp16)av.w;
        a0 = __builtin_amdgcn_mfma_f32_16x16x16f16(af, bf0[ec], a0, 0, 0, 0);
        a1 = __builtin_amdgcn_mfma_f32_16x16x16f16(af, bf1[ec], a1, 0, 0, 0);
    }
    const int nt = s * 128 + wid * 16;
    const int nb4 = nt + 4 * lg;
#pragma unroll
    for (int t = 0; t < 2; t++) {
        const v4f ac = t ? a1 : a0;
        const float4 m = t ? m1 : m0;
        v4h wf;
        float ws = 0.f;
        if (nt + 15 < NN) {
            float e0 = __expf(2.f * ac[0]);
            float e1 = __expf(2.f * ac[1]);
            float e2 = __expf(2.f * ac[2]);
            float e3 = __expf(2.f * ac[3]);
            float w0 = __expf(fmaf(-20.f, __builtin_amdgcn_rcpf(e0 + 1.f), m.x));
            float w1 = __expf(fmaf(-20.f, __builtin_amdgcn_rcpf(e1 + 1.f), m.y));
            float w2 = __expf(fmaf(-20.f, __builtin_amdgcn_rcpf(e2 + 1.f), m.z));
            float w3 = __expf(fmaf(-20.f, __builtin_amdgcn_rcpf(e3 + 1.f), m.w));
            ws = (w0 + w1) + (w2 + w3);
            wf[0] = (__fp16)w0; wf[1] = (__fp16)w1; wf[2] = (__fp16)w2; wf[3] = (__fp16)w3;
        } else {
            float w0 = 0.f, w1 = 0.f, w2 = 0.f, w3 = 0.f;
            if (nb4 + 0 < NN) {
                float e = __expf(2.f * ac[0]);
                w0 = __expf(fmaf(-20.f, __builtin_amdgcn_rcpf(e + 1.f), m.x));
            }
            if (nb4 + 1 < NN) {
                float e = __expf(2.f * ac[1]);
                w1 = __expf(fmaf(-20.f, __builtin_amdgcn_rcpf(e + 1.f), m.y));
            }
            if (nb4 + 2 < NN) {
                float e = __expf(2.f * ac[2]);
                w2 = __expf(fmaf(-20.f, __builtin_amdgcn_rcpf(e + 1.f), m.z));
            }
            if (nb4 + 3 < NN) {
                float e = __expf(2.f * ac[3]);
                w3 = __expf(fmaf(-20.f, __builtin_amdgcn_rcpf(e + 1.f), m.w));
            }
            ws = (w0 + w1) + (w2 + w3);
            wf[0] = (__fp16)w0; wf[1] = (__fp16)w1; wf[2] = (__fp16)w2; wf[3] = (__fp16)w3;
        }
        if (t) ls1 += ws; else ls0 += ws;
        *(v4h*)&probs[(t * 16 + lp) * 1028 + nb4] = wf;
    }
}

__global__ __launch_bounds__(512, 4) void k5_final(const float* __restrict__ nodes,
                                                   const __fp16* __restrict__ Mh,
                                                   const float* __restrict__ mask,
                                                   float* __restrict__ out) {
    __shared__ __fp16 probs[32 * 1028];   // 65,792 B
    __shared__ float rowsum[32];
    __shared__ float rowinv[32];
    const int tid = threadIdx.x;
    const int bid = blockIdx.x;          // 512 = 64 b x 8 pt; b&7 = bid&7 (XCD)
    const int xcd = bid & 7;
    const int pt = (bid >> 3) & 7;
    const int b = ((bid >> 6) << 3) | xcd;
    const int p0 = pt * 32;

    if (tid < 32) rowsum[tid] = 0.f;

    const int wid = tid >> 6, lane = tid & 63;
    const int lp = lane & 15, lg = lane >> 4;

    v4h bf0[8], bf1[8];
    {
        const __fp16* mh0 = Mh + (size_t)(b * PP + p0 + lp) * 128;
        const __fp16* mh1 = mh0 + (size_t)16 * 128;
#pragma unroll
        for (int ec = 0; ec < 8; ec++) {
            bf0[ec] = *(const v4h*)&mh0[ec * 16 + 4 * lg];
            bf1[ec] = *(const v4h*)&mh1[ec * 16 + 4 * lg];
        }
    }
    __syncthreads();

    float ls0 = 0.f, ls1 = 0.f;
    const float* nbase = nodes + (size_t)b * NN * 128;
    const float* mk0 = mask + (size_t)(b * PP + p0 + lp) * NN;
    const float* mk1 = mk0 + (size_t)16 * NN;

    // ping-pong register buffers; prefetch step s+1 while computing step s
    float4 nbA[8], nbB[8];
    k5_pref(0, wid, lp, lg, nbase, nbA);
    for (int s2 = 0; s2 < 4; s2++) {
        const int s = 2 * s2;
        k5_pref(s + 1, wid, lp, lg, nbase, nbB);
        k5_comp(s, wid, lp, lg, bf0, bf1, nbA, mk0, mk1, ls0, ls1, probs);
        if (s2 < 3) k5_pref(s + 2, wid, lp, lg, nbase, nbA);
        k5_comp(s + 1, wid, lp, lg, bf0, bf1, nbB, mk0, mk1, ls0, ls1, probs);
    }

    ls0 += __shfl_xor(ls0, 16);
    ls0 += __shfl_xor(ls0, 32);
    ls1 += __shfl_xor(ls1, 16);
    ls1 += __shfl_xor(ls1, 32);
    if (lane < 16) {
        atomicAdd(&rowsum[lane], ls0);
        atomicAdd(&rowsum[16 + lane], ls1);
    }
    __syncthreads();
    if (tid < 32) rowinv[tid] = 1.f / rowsum[tid];
    __syncthreads();

    if (tid < 500) {
        const int rg = tid / 250;             // 0..1: row-group of 16
        const int c4 = (tid - rg * 250) * 4;  // 0..996
        const size_t obase = (size_t)(b * PP + p0 + rg * 16) * NN;
#pragma unroll 4
        for (int r = 0; r < 16; r++) {
            v4h pv = *(const v4h*)&probs[(rg * 16 + r) * 1028 + c4];
            float inv = rowinv[rg * 16 + r];
            float4 ov;
            ov.x = (float)pv[0] * inv;
            ov.y = (float)pv[1] * inv;
            ov.z = (float)pv[2] * inv;
            ov.w = (float)pv[3] * inv;
            *(float4*)&out[obase + (size_t)r * NN + c4] = ov;
        }
    }
}

extern "C" void kernel_launch(void* const* d_in, const int* in_sizes, int n_in,
                              void* d_out, int out_size, void* d_ws, size_t ws_size,
                              hipStream_t stream) {
    const float* nodes = (const float*)d_in[0];
    const float* ln    = (const float*)d_in[1];
    const float* attr  = (const float*)d_in[2];
    const float* mask  = (const float*)d_in[3];
    const float* Wq    = (const float*)d_in[4];
    const float* Wk    = (const float*)d_in[5];
    const float* Wv    = (const float*)d_in[6];
    const float* Wo    = (const float*)d_in[7];
    const float* bo    = (const float*)d_in[8];
    float* out = (float*)d_out;

    // workspace layout (halfs): Aout fp16, Qh, Mh  (12.6 MB total)
    __fp16* AoutH = (__fp16*)d_ws;                     // 2,097,152 halfs
    __fp16* Qh    = AoutH + 2097152;                   // 2,097,152 halfs
    __fp16* Mhh   = Qh + 2097152;                      // 2,097,152 halfs

    // d_out doubles as fp16 K/V scratch (fully rewritten by k5 every launch)
    __fp16* Kf = (__fp16*)d_out;
    __fp16* Vt = Kf + (size_t)BB * HH * NP * 16;

    hipLaunchKernelGGL(k1_qproj, dim3(256), dim3(256), 0, stream, ln, attr, Wq, Qh);
    hipLaunchKernelGGL(k2_kv, dim3(16, 64, 2), dim3(256), 0, stream, nodes, Wk, Wv, Kf, Vt);
    hipLaunchKernelGGL(k3_attn, dim3(1024), dim3(256), 0, stream, Qh, Kf, Vt, mask, AoutH);
    hipLaunchKernelGGL(k4_mh, dim3(256), dim3(256), 0, stream, AoutH, Wo, bo, Mhh);
    hipLaunchKernelGGL(k5_final, dim3(512), dim3(512), 0, stream, nodes, Mhh, mask, out);
}